// Round 2
// baseline (1132.037 us; speedup 1.0000x reference)
//
#include <hip/hip_runtime.h>
#include <math.h>

// Problem constants (from reference)
#define N_NODES  50000
#define N_EDGES  800000
#define N_GRAPHS 2500
#define IN_DIM   128
#define HID      128
#define HEADS    2
#define HC       256   // HEADS*HID

typedef unsigned short u16;

// bf16 helpers (manual, no dtype headers needed)
__device__ inline float bf2f(u16 u) {
    union { unsigned int i; float f; } c; c.i = ((unsigned int)u) << 16; return c.f;
}
__device__ inline u16 f2bf(float x) {
    union { float f; unsigned int i; } c; c.f = x;
    unsigned int r = c.i + 0x7FFFu + ((c.i >> 16) & 1u);
    return (u16)(r >> 16);
}

// ---------------------------------------------------------------------------
// int64-vs-int32 autodetect: sample odd int32 positions; int64 payloads
// (values < 2^31) have zero high words there. *flag = 1 if int64.
// ---------------------------------------------------------------------------
__global__ void detect_i64_kernel(const int* __restrict__ p, int odd_base, int nsamp,
                                  int* __restrict__ flag) {
    __shared__ int nz;
    if (threadIdx.x == 0) nz = 0;
    __syncthreads();
    int any = 0;
    for (int t = threadIdx.x; t < nsamp; t += 256) {
        if (p[odd_base + 2 * t] != 0) any = 1;
    }
    if (any) atomicAdd(&nz, 1);
    __syncthreads();
    if (threadIdx.x == 0) *flag = (nz == 0) ? 1 : 0;
}

// ---------------------------------------------------------------------------
// CSR build: histogram -> scan -> scatter  (dst-sorted adjacency)
// ---------------------------------------------------------------------------
__global__ void hist_kernel(const int* __restrict__ ei, const int* __restrict__ flag,
                            int* __restrict__ deg, int E) {
    int i = blockIdx.x * blockDim.x + threadIdx.x;
    if (i >= E) return;
    int f = *flag;
    int d = f ? ei[2 * ((size_t)E + i)] : ei[(size_t)E + i];
    if ((unsigned)d < (unsigned)N_NODES) atomicAdd(&deg[d], 1);
}

// 256 threads/block, 4 elements/thread -> 1024 elems per block
__global__ void scan_local_kernel(const int* __restrict__ deg, int* __restrict__ rowptr,
                                  int* __restrict__ bsums, int n) {
    __shared__ int sh[256];
    int t = threadIdx.x;
    int base = blockIdx.x * 1024 + t * 4;
    int d0 = (base + 0 < n) ? deg[base + 0] : 0;
    int d1 = (base + 1 < n) ? deg[base + 1] : 0;
    int d2 = (base + 2 < n) ? deg[base + 2] : 0;
    int d3 = (base + 3 < n) ? deg[base + 3] : 0;
    sh[t] = d0 + d1 + d2 + d3;
    __syncthreads();
    for (int off = 1; off < 256; off <<= 1) {
        int val = 0;
        if (t >= off) val = sh[t - off];
        __syncthreads();
        if (t >= off) sh[t] += val;
        __syncthreads();
    }
    int excl = (t > 0) ? sh[t - 1] : 0;
    if (t == 255) bsums[blockIdx.x] = sh[255];
    if (base + 0 < n) rowptr[base + 0] = excl;
    if (base + 1 < n) rowptr[base + 1] = excl + d0;
    if (base + 2 < n) rowptr[base + 2] = excl + d0 + d1;
    if (base + 3 < n) rowptr[base + 3] = excl + d0 + d1 + d2;
}

// exclusive-scan block sums; also writes total into rowptr[N]
__global__ void scan_bsums_kernel(int* __restrict__ bsums, int nb, int* __restrict__ rowptr_last) {
    if (threadIdx.x == 0 && blockIdx.x == 0) {
        int run = 0;
        for (int i = 0; i < nb; ++i) { int v = bsums[i]; bsums[i] = run; run += v; }
        *rowptr_last = run;
    }
}

__global__ void scan_add_kernel(int* __restrict__ rowptr, const int* __restrict__ bsums,
                                int* __restrict__ cursor, int n) {
    int i = blockIdx.x * blockDim.x + threadIdx.x;
    if (i < n) {
        int r = rowptr[i] + bsums[i >> 10];
        rowptr[i] = r;
        cursor[i] = r;
    }
}

__global__ void scatter_kernel(const int* __restrict__ ei, const float* __restrict__ ea,
                               const int* __restrict__ flag, int* __restrict__ cursor,
                               int* __restrict__ srcs, float* __restrict__ eas, int E) {
    int i = blockIdx.x * blockDim.x + threadIdx.x;
    if (i >= E) return;
    int f = *flag;
    int s = f ? ei[2 * (size_t)i] : ei[i];
    int d = f ? ei[2 * ((size_t)E + i)] : ei[(size_t)E + i];
    if ((unsigned)d >= (unsigned)N_NODES) return;
    if ((unsigned)s >= (unsigned)N_NODES) s = 0;
    int p = atomicAdd(&cursor[d], 1);
    srcs[p] = s;
    eas[p]  = ea[i];
}

// ---------------------------------------------------------------------------
// GEMM: C[M,N] = bf16( A[M,K] @ W[K,N] + bias[N] ), fp32 accumulate.
// A is fp32 (layer 1) or bf16 (layer 2) via template.
// 64x64 tile, BK=32, 256 threads, 4x4 per thread.
// ---------------------------------------------------------------------------
#define BM 64
#define BN 64
#define BK 32

template <typename AT>
__global__ __launch_bounds__(256) void gemm_bias(
    const AT* __restrict__ A, const float* __restrict__ W,
    const float* __restrict__ bias, u16* __restrict__ C,
    int M, int K, int N)
{
    __shared__ float As[BK][BM + 4];
    __shared__ float Bs[BK][BN];
    int t = threadIdx.x;
    int tm = t >> 4;    // 0..15
    int tn = t & 15;    // 0..15
    int row0 = blockIdx.x * BM;
    int col0 = blockIdx.y * BN;
    float acc[4][4];
#pragma unroll
    for (int i = 0; i < 4; ++i)
#pragma unroll
        for (int j = 0; j < 4; ++j) acc[i][j] = 0.f;

    for (int k0 = 0; k0 < K; k0 += BK) {
#pragma unroll
        for (int j = t; j < (BM * BK) / 4; j += 256) {
            int r = (j * 4) / BK;      // 0..63
            int c = (j * 4) % BK;      // 0,4,...,28
            int gr = row0 + r;
            float ax, ay, az, aw;
            if (gr < M) {
                if constexpr (sizeof(AT) == 4) {
                    float4 a = *(const float4*)&A[(size_t)gr * K + k0 + c];
                    ax = a.x; ay = a.y; az = a.z; aw = a.w;
                } else {
                    ushort4 a = *(const ushort4*)&A[(size_t)gr * K + k0 + c];
                    ax = bf2f(a.x); ay = bf2f(a.y); az = bf2f(a.z); aw = bf2f(a.w);
                }
            } else { ax = ay = az = aw = 0.f; }
            As[c + 0][r] = ax; As[c + 1][r] = ay; As[c + 2][r] = az; As[c + 3][r] = aw;
        }
#pragma unroll
        for (int j = t; j < (BK * BN) / 4; j += 256) {
            int r = (j * 4) / BN;      // 0..31
            int c = (j * 4) % BN;
            *(float4*)&Bs[r][c] = *(const float4*)&W[(size_t)(k0 + r) * N + col0 + c];
        }
        __syncthreads();
#pragma unroll
        for (int kk = 0; kk < BK; ++kk) {
            float4 a4 = *(const float4*)&As[kk][tm * 4];
            float4 b4 = *(const float4*)&Bs[kk][tn * 4];
            acc[0][0] = fmaf(a4.x, b4.x, acc[0][0]);
            acc[0][1] = fmaf(a4.x, b4.y, acc[0][1]);
            acc[0][2] = fmaf(a4.x, b4.z, acc[0][2]);
            acc[0][3] = fmaf(a4.x, b4.w, acc[0][3]);
            acc[1][0] = fmaf(a4.y, b4.x, acc[1][0]);
            acc[1][1] = fmaf(a4.y, b4.y, acc[1][1]);
            acc[1][2] = fmaf(a4.y, b4.z, acc[1][2]);
            acc[1][3] = fmaf(a4.y, b4.w, acc[1][3]);
            acc[2][0] = fmaf(a4.z, b4.x, acc[2][0]);
            acc[2][1] = fmaf(a4.z, b4.y, acc[2][1]);
            acc[2][2] = fmaf(a4.z, b4.z, acc[2][2]);
            acc[2][3] = fmaf(a4.z, b4.w, acc[2][3]);
            acc[3][0] = fmaf(a4.w, b4.x, acc[3][0]);
            acc[3][1] = fmaf(a4.w, b4.y, acc[3][1]);
            acc[3][2] = fmaf(a4.w, b4.z, acc[3][2]);
            acc[3][3] = fmaf(a4.w, b4.w, acc[3][3]);
        }
        __syncthreads();
    }
    float4 b4 = *(const float4*)&bias[col0 + tn * 4];
#pragma unroll
    for (int i = 0; i < 4; ++i) {
        int gr = row0 + tm * 4 + i;
        if (gr < M) {
            ushort4 o;
            o.x = f2bf(acc[i][0] + b4.x);
            o.y = f2bf(acc[i][1] + b4.y);
            o.z = f2bf(acc[i][2] + b4.z);
            o.w = f2bf(acc[i][3] + b4.w);
            *(ushort4*)&C[(size_t)gr * N + col0 + tn * 4] = o;
        }
    }
}

// ---------------------------------------------------------------------------
// Attention layer 1: wave per node, online softmax over incoming edges.
// q,k,v,skip bf16 [N,256]; lane covers cols lane*4..+3; head = lane>>5.
// Epilogue: concat + skip, ReLU -> h bf16 [N,256]. h may alias q (row-local).
// ---------------------------------------------------------------------------
__global__ __launch_bounds__(256) void attn_node_l1(
    const u16* __restrict__ q, const u16* __restrict__ k,
    const u16* __restrict__ v, const float* __restrict__ We,
    const u16* __restrict__ skip, const int* __restrict__ rowptr,
    const int* __restrict__ srcs, const float* __restrict__ eas,
    u16* __restrict__ h, int N)
{
    int wave = (blockIdx.x * blockDim.x + threadIdx.x) >> 6;
    int lane = threadIdx.x & 63;
    if (wave >= N) return;
    int n = wave;
    const float scale = 0.08838834764831845f;  // 1/sqrt(128)

    ushort4 qu = *(const ushort4*)&q[(size_t)n * HC + lane * 4];
    float4 q4 = make_float4(bf2f(qu.x), bf2f(qu.y), bf2f(qu.z), bf2f(qu.w));
    float4 w4 = *(const float4*)&We[lane * 4];
    int e0 = rowptr[n], e1 = rowptr[n + 1];
    float m = -INFINITY, l = 0.f;
    float4 acc = make_float4(0.f, 0.f, 0.f, 0.f);

    for (int e = e0; e < e1; ++e) {
        int s = srcs[e];
        float a_e = eas[e];
        ushort4 ku = *(const ushort4*)&k[(size_t)s * HC + lane * 4];
        ushort4 vu = *(const ushort4*)&v[(size_t)s * HC + lane * 4];
        float kx = fmaf(a_e, w4.x, bf2f(ku.x));
        float ky = fmaf(a_e, w4.y, bf2f(ku.y));
        float kz = fmaf(a_e, w4.z, bf2f(ku.z));
        float kw = fmaf(a_e, w4.w, bf2f(ku.w));
        float part = q4.x * kx + q4.y * ky + q4.z * kz + q4.w * kw;
        part += __shfl_xor(part, 1);
        part += __shfl_xor(part, 2);
        part += __shfl_xor(part, 4);
        part += __shfl_xor(part, 8);
        part += __shfl_xor(part, 16);
        float alpha = part * scale;
        float mnew = fmaxf(m, alpha);
        float corr = __expf(m - mnew);     // exp(-inf)=0 on first edge
        float p = __expf(alpha - mnew);
        l = l * corr + p;
        acc.x = acc.x * corr + p * fmaf(a_e, w4.x, bf2f(vu.x));
        acc.y = acc.y * corr + p * fmaf(a_e, w4.y, bf2f(vu.y));
        acc.z = acc.z * corr + p * fmaf(a_e, w4.z, bf2f(vu.z));
        acc.w = acc.w * corr + p * fmaf(a_e, w4.w, bf2f(vu.w));
        m = mnew;
    }
    float inv = (l > 0.f) ? 1.f / l : 0.f;
    ushort4 su = *(const ushort4*)&skip[(size_t)n * HC + lane * 4];
    ushort4 o;
    o.x = f2bf(fmaxf(0.f, acc.x * inv + bf2f(su.x)));
    o.y = f2bf(fmaxf(0.f, acc.y * inv + bf2f(su.y)));
    o.z = f2bf(fmaxf(0.f, acc.z * inv + bf2f(su.z)));
    o.w = f2bf(fmaxf(0.f, acc.w * inv + bf2f(su.w)));
    *(ushort4*)&h[(size_t)n * HC + lane * 4] = o;
}

// ---------------------------------------------------------------------------
// Attention layer 2: mean over heads + skip (no relu). skip bf16 [N,128],
// output h2 fp32 [N,128].
// ---------------------------------------------------------------------------
__global__ __launch_bounds__(256) void attn_node_l2(
    const u16* __restrict__ q, const u16* __restrict__ k,
    const u16* __restrict__ v, const float* __restrict__ We,
    const u16* __restrict__ skip, const int* __restrict__ rowptr,
    const int* __restrict__ srcs, const float* __restrict__ eas,
    float* __restrict__ h, int N)
{
    int wave = (blockIdx.x * blockDim.x + threadIdx.x) >> 6;
    int lane = threadIdx.x & 63;
    if (wave >= N) return;
    int n = wave;
    const float scale = 0.08838834764831845f;

    ushort4 qu = *(const ushort4*)&q[(size_t)n * HC + lane * 4];
    float4 q4 = make_float4(bf2f(qu.x), bf2f(qu.y), bf2f(qu.z), bf2f(qu.w));
    float4 w4 = *(const float4*)&We[lane * 4];
    int e0 = rowptr[n], e1 = rowptr[n + 1];
    float m = -INFINITY, l = 0.f;
    float4 acc = make_float4(0.f, 0.f, 0.f, 0.f);

    for (int e = e0; e < e1; ++e) {
        int s = srcs[e];
        float a_e = eas[e];
        ushort4 ku = *(const ushort4*)&k[(size_t)s * HC + lane * 4];
        ushort4 vu = *(const ushort4*)&v[(size_t)s * HC + lane * 4];
        float kx = fmaf(a_e, w4.x, bf2f(ku.x));
        float ky = fmaf(a_e, w4.y, bf2f(ku.y));
        float kz = fmaf(a_e, w4.z, bf2f(ku.z));
        float kw = fmaf(a_e, w4.w, bf2f(ku.w));
        float part = q4.x * kx + q4.y * ky + q4.z * kz + q4.w * kw;
        part += __shfl_xor(part, 1);
        part += __shfl_xor(part, 2);
        part += __shfl_xor(part, 4);
        part += __shfl_xor(part, 8);
        part += __shfl_xor(part, 16);
        float alpha = part * scale;
        float mnew = fmaxf(m, alpha);
        float corr = __expf(m - mnew);
        float p = __expf(alpha - mnew);
        l = l * corr + p;
        acc.x = acc.x * corr + p * fmaf(a_e, w4.x, bf2f(vu.x));
        acc.y = acc.y * corr + p * fmaf(a_e, w4.y, bf2f(vu.y));
        acc.z = acc.z * corr + p * fmaf(a_e, w4.z, bf2f(vu.z));
        acc.w = acc.w * corr + p * fmaf(a_e, w4.w, bf2f(vu.w));
        m = mnew;
    }
    float inv = (l > 0.f) ? 1.f / l : 0.f;
    float ox = acc.x * inv, oy = acc.y * inv, oz = acc.z * inv, ow = acc.w * inv;
    // mean over heads: lane^32 holds the other head, same channel
    ox = 0.5f * (ox + __shfl_xor(ox, 32));
    oy = 0.5f * (oy + __shfl_xor(oy, 32));
    oz = 0.5f * (oz + __shfl_xor(oz, 32));
    ow = 0.5f * (ow + __shfl_xor(ow, 32));
    if (lane < 32) {
        ushort4 su = *(const ushort4*)&skip[(size_t)n * HID + lane * 4];
        float4 o;
        o.x = ox + bf2f(su.x); o.y = oy + bf2f(su.y);
        o.z = oz + bf2f(su.z); o.w = ow + bf2f(su.w);
        *(float4*)&h[(size_t)n * HID + lane * 4] = o;
    }
}

// ---------------------------------------------------------------------------
// Global mean pool
// ---------------------------------------------------------------------------
__global__ void pool_sum_kernel(const float* __restrict__ h2, const int* __restrict__ batch,
                                const int* __restrict__ flag,
                                float* __restrict__ sums, int* __restrict__ cnts, int N) {
    int idx = blockIdx.x * blockDim.x + threadIdx.x;
    int n = idx >> 5;
    int c4 = idx & 31;
    if (n >= N) return;
    int f = *flag;
    int g = f ? batch[2 * (size_t)n] : batch[n];
    if ((unsigned)g >= (unsigned)N_GRAPHS) g = 0;
    float4 x4 = *(const float4*)&h2[(size_t)n * HID + c4 * 4];
    atomicAdd(&sums[(size_t)g * HID + c4 * 4 + 0], x4.x);
    atomicAdd(&sums[(size_t)g * HID + c4 * 4 + 1], x4.y);
    atomicAdd(&sums[(size_t)g * HID + c4 * 4 + 2], x4.z);
    atomicAdd(&sums[(size_t)g * HID + c4 * 4 + 3], x4.w);
    if (c4 == 0) atomicAdd(&cnts[g], 1);
}

__global__ void pool_div_kernel(const float* __restrict__ sums, const int* __restrict__ cnts,
                                float* __restrict__ out) {
    int idx = blockIdx.x * blockDim.x + threadIdx.x;
    int g = idx >> 5;
    int c4 = idx & 31;
    if (g >= N_GRAPHS) return;
    float inv = 1.f / fmaxf((float)cnts[g], 1.f);
    float4 s4 = *(const float4*)&sums[(size_t)g * HID + c4 * 4];
    float4 o;
    o.x = s4.x * inv; o.y = s4.y * inv; o.z = s4.z * inv; o.w = s4.w * inv;
    *(float4*)&out[(size_t)g * HID + c4 * 4] = o;
}

// ---------------------------------------------------------------------------
// Launch. Workspace layout ~124 MB total (was ~290 MB: theory = ws overflow
// caused the round-1 abort). B0..B3 are 25.6 MB bf16 [N,256] buffers with
// aliasing: h1 overwrites B0 (row-local), h2 (fp32 [N,128], same byte size)
// overwrites B0 again.
// ---------------------------------------------------------------------------
extern "C" void kernel_launch(void* const* d_in, const int* in_sizes, int n_in,
                              void* d_out, int out_size, void* d_ws, size_t ws_size,
                              hipStream_t stream) {
    const float* x    = (const float*)d_in[0];
    const int*   ei   = (const int*)d_in[1];   // [2, E] (int32 or int64 — autodetected)
    const int*   batch= (const int*)d_in[2];
    const float* ea   = (const float*)d_in[3];
    const float* Wq1  = (const float*)d_in[4];
    const float* bq1  = (const float*)d_in[5];
    const float* Wk1  = (const float*)d_in[6];
    const float* bk1  = (const float*)d_in[7];
    const float* Wv1  = (const float*)d_in[8];
    const float* bv1  = (const float*)d_in[9];
    const float* We1  = (const float*)d_in[10];
    const float* Ws1  = (const float*)d_in[11];
    const float* bs1  = (const float*)d_in[12];
    const float* Wq2  = (const float*)d_in[13];
    const float* bq2  = (const float*)d_in[14];
    const float* Wk2  = (const float*)d_in[15];
    const float* bk2  = (const float*)d_in[16];
    const float* Wv2  = (const float*)d_in[17];
    const float* bv2  = (const float*)d_in[18];
    const float* We2  = (const float*)d_in[19];
    const float* Ws2  = (const float*)d_in[20];
    const float* bs2  = (const float*)d_in[21];
    float* out = (float*)d_out;

    char* ws = (char*)d_ws;
    size_t off = 0;
    auto alloc = [&](size_t bytes) -> void* {
        void* p = ws + off;
        off += (bytes + 255) & ~(size_t)255;
        return p;
    };
    int*   flag_ei = (int*)alloc(4);
    int*   flag_b  = (int*)alloc(4);
    int*   deg     = (int*)alloc((size_t)N_NODES * 4);
    int*   rowptr  = (int*)alloc((size_t)(N_NODES + 1) * 4);
    int*   cursor  = (int*)alloc((size_t)N_NODES * 4);
    int*   bsums   = (int*)alloc(64 * 4);
    int*   srcs    = (int*)alloc((size_t)N_EDGES * 4);
    float* eas     = (float*)alloc((size_t)N_EDGES * 4);
    u16*   B0      = (u16*)alloc((size_t)N_NODES * HC * 2);   // q1 / h1 / h2(fp32 [N,128])
    u16*   B1      = (u16*)alloc((size_t)N_NODES * HC * 2);   // k1 / q2
    u16*   B2      = (u16*)alloc((size_t)N_NODES * HC * 2);   // v1 / k2
    u16*   B3      = (u16*)alloc((size_t)N_NODES * HC * 2);   // skip1 / v2
    u16*   B4      = (u16*)alloc((size_t)N_NODES * HID * 2);  // skip2
    float* psum    = (float*)alloc((size_t)N_GRAPHS * HID * 4);
    int*   cnts    = (int*)alloc((size_t)N_GRAPHS * 4);

    hipMemsetAsync(deg, 0, (size_t)N_NODES * 4, stream);
    hipMemsetAsync(psum, 0, (size_t)N_GRAPHS * HID * 4, stream);
    hipMemsetAsync(cnts, 0, (size_t)N_GRAPHS * 4, stream);

    const int E = N_EDGES;

    // dtype autodetect (odd positions = int64 high words = 0 for values < 2^31)
    detect_i64_kernel<<<1, 256, 0, stream>>>(ei, 1, 1024, flag_ei);       // ints 1..2047: valid both dtypes
    detect_i64_kernel<<<1, 256, 0, stream>>>(batch, 40001, 1024, flag_b); // ints 40001..42047: valid both; int32 values ~2000 != 0

    // CSR by dst
    hist_kernel<<<(E + 255) / 256, 256, 0, stream>>>(ei, flag_ei, deg, E);
    int nb = (N_NODES + 1023) / 1024;  // 49
    scan_local_kernel<<<nb, 256, 0, stream>>>(deg, rowptr, bsums, N_NODES);
    scan_bsums_kernel<<<1, 64, 0, stream>>>(bsums, nb, rowptr + N_NODES);
    scan_add_kernel<<<(N_NODES + 255) / 256, 256, 0, stream>>>(rowptr, bsums, cursor, N_NODES);
    scatter_kernel<<<(E + 255) / 256, 256, 0, stream>>>(ei, ea, flag_ei, cursor, srcs, eas, E);

    // Layer 1 GEMMs: [50000,128] @ [128,256], fp32 A -> bf16 out
    dim3 g256((N_NODES + BM - 1) / BM, HC / BN);
    gemm_bias<float><<<g256, 256, 0, stream>>>(x, Wq1, bq1, B0, N_NODES, IN_DIM, HC);
    gemm_bias<float><<<g256, 256, 0, stream>>>(x, Wk1, bk1, B1, N_NODES, IN_DIM, HC);
    gemm_bias<float><<<g256, 256, 0, stream>>>(x, Wv1, bv1, B2, N_NODES, IN_DIM, HC);
    gemm_bias<float><<<g256, 256, 0, stream>>>(x, Ws1, bs1, B3, N_NODES, IN_DIM, HC);

    // h1 -> B0 (aliases q1; safe: wave n reads q row n before writing h row n)
    attn_node_l1<<<N_NODES / 4, 256, 0, stream>>>(B0, B1, B2, We1, B3, rowptr, srcs, eas, B0, N_NODES);

    // Layer 2 GEMMs: [50000,256] @ [256,256] (and skip [256,128]), bf16 A -> bf16 out
    gemm_bias<u16><<<g256, 256, 0, stream>>>(B0, Wq2, bq2, B1, N_NODES, HC, HC);
    gemm_bias<u16><<<g256, 256, 0, stream>>>(B0, Wk2, bk2, B2, N_NODES, HC, HC);
    gemm_bias<u16><<<g256, 256, 0, stream>>>(B0, Wv2, bv2, B3, N_NODES, HC, HC);
    dim3 g128((N_NODES + BM - 1) / BM, HID / BN);
    gemm_bias<u16><<<g128, 256, 0, stream>>>(B0, Ws2, bs2, B4, N_NODES, HC, HID);

    // h2 (fp32 [N,128]) -> B0 (h1 dead after layer-2 GEMMs; attn_l2 doesn't read B0)
    attn_node_l2<<<N_NODES / 4, 256, 0, stream>>>(B1, B2, B3, We2, B4, rowptr, srcs, eas, (float*)B0, N_NODES);

    // Global mean pool
    pool_sum_kernel<<<(N_NODES * 32 + 255) / 256, 256, 0, stream>>>((const float*)B0, batch, flag_b, psum, cnts, N_NODES);
    pool_div_kernel<<<(N_GRAPHS * 32 + 255) / 256, 256, 0, stream>>>(psum, cnts, out);
}

// Round 3
// 662.210 us; speedup vs baseline: 1.7095x; 1.7095x over previous
//
#include <hip/hip_runtime.h>
#include <math.h>

// Problem constants (from reference)
#define N_NODES  50000
#define N_EDGES  800000
#define N_GRAPHS 2500
#define IN_DIM   128
#define HID      128
#define HEADS    2
#define HC       256   // HEADS*HID

typedef unsigned short u16;
typedef short  s8v  __attribute__((ext_vector_type(8)));   // 8 bf16 = 4 VGPRs (MFMA A/B frag)
typedef float  f4v  __attribute__((ext_vector_type(4)));   // MFMA C/D frag

// bf16 helpers
__device__ inline float bf2f(u16 u) {
    union { unsigned int i; float f; } c; c.i = ((unsigned int)u) << 16; return c.f;
}
__device__ inline u16 f2bf(float x) {
    union { float f; unsigned int i; } c; c.f = x;
    unsigned int r = c.i + 0x7FFFu + ((c.i >> 16) & 1u);
    return (u16)(r >> 16);
}

// ---------------------------------------------------------------------------
// int64-vs-int32 autodetect (odd int32 positions are int64 high words == 0)
// ---------------------------------------------------------------------------
__global__ void detect_i64_kernel(const int* __restrict__ p, int odd_base, int nsamp,
                                  int* __restrict__ flag) {
    __shared__ int nz;
    if (threadIdx.x == 0) nz = 0;
    __syncthreads();
    int any = 0;
    for (int t = threadIdx.x; t < nsamp; t += 256) {
        if (p[odd_base + 2 * t] != 0) any = 1;
    }
    if (any) atomicAdd(&nz, 1);
    __syncthreads();
    if (threadIdx.x == 0) *flag = (nz == 0) ? 1 : 0;
}

// ---------------------------------------------------------------------------
// CSR build: histogram -> scan -> scatter  (dst-sorted adjacency)
// ---------------------------------------------------------------------------
__global__ void hist_kernel(const int* __restrict__ ei, const int* __restrict__ flag,
                            int* __restrict__ deg, int E) {
    int i = blockIdx.x * blockDim.x + threadIdx.x;
    if (i >= E) return;
    int f = *flag;
    int d = f ? ei[2 * ((size_t)E + i)] : ei[(size_t)E + i];
    if ((unsigned)d < (unsigned)N_NODES) atomicAdd(&deg[d], 1);
}

__global__ void scan_local_kernel(const int* __restrict__ deg, int* __restrict__ rowptr,
                                  int* __restrict__ bsums, int n) {
    __shared__ int sh[256];
    int t = threadIdx.x;
    int base = blockIdx.x * 1024 + t * 4;
    int d0 = (base + 0 < n) ? deg[base + 0] : 0;
    int d1 = (base + 1 < n) ? deg[base + 1] : 0;
    int d2 = (base + 2 < n) ? deg[base + 2] : 0;
    int d3 = (base + 3 < n) ? deg[base + 3] : 0;
    sh[t] = d0 + d1 + d2 + d3;
    __syncthreads();
    for (int off = 1; off < 256; off <<= 1) {
        int val = 0;
        if (t >= off) val = sh[t - off];
        __syncthreads();
        if (t >= off) sh[t] += val;
        __syncthreads();
    }
    int excl = (t > 0) ? sh[t - 1] : 0;
    if (t == 255) bsums[blockIdx.x] = sh[255];
    if (base + 0 < n) rowptr[base + 0] = excl;
    if (base + 1 < n) rowptr[base + 1] = excl + d0;
    if (base + 2 < n) rowptr[base + 2] = excl + d0 + d1;
    if (base + 3 < n) rowptr[base + 3] = excl + d0 + d1 + d2;
}

__global__ void scan_bsums_kernel(int* __restrict__ bsums, int nb, int* __restrict__ rowptr_last) {
    if (threadIdx.x == 0 && blockIdx.x == 0) {
        int run = 0;
        for (int i = 0; i < nb; ++i) { int v = bsums[i]; bsums[i] = run; run += v; }
        *rowptr_last = run;
    }
}

__global__ void scan_add_kernel(int* __restrict__ rowptr, const int* __restrict__ bsums,
                                int* __restrict__ cursor, int n) {
    int i = blockIdx.x * blockDim.x + threadIdx.x;
    if (i < n) {
        int r = rowptr[i] + bsums[i >> 10];
        rowptr[i] = r;
        cursor[i] = r;
    }
}

__global__ void scatter_kernel(const int* __restrict__ ei, const float* __restrict__ ea,
                               const int* __restrict__ flag, int* __restrict__ cursor,
                               int* __restrict__ srcs, float* __restrict__ eas, int E) {
    int i = blockIdx.x * blockDim.x + threadIdx.x;
    if (i >= E) return;
    int f = *flag;
    int s = f ? ei[2 * (size_t)i] : ei[i];
    int d = f ? ei[2 * ((size_t)E + i)] : ei[(size_t)E + i];
    if ((unsigned)d >= (unsigned)N_NODES) return;
    if ((unsigned)s >= (unsigned)N_NODES) s = 0;
    int p = atomicAdd(&cursor[d], 1);
    srcs[p] = s;
    eas[p]  = ea[i];
}

// ---------------------------------------------------------------------------
// Weight prep: fp32 [K,Nw] weights -> concatenated bf16 B^T [Ncat][K] (+ bias cat)
// ---------------------------------------------------------------------------
__global__ void prep_w1(const float* __restrict__ Wq, const float* __restrict__ Wk,
                        const float* __restrict__ Wv, const float* __restrict__ Ws,
                        const float* __restrict__ bq, const float* __restrict__ bk,
                        const float* __restrict__ bv, const float* __restrict__ bs,
                        u16* __restrict__ WT, float* __restrict__ bcat) {
    int t = blockIdx.x * 256 + threadIdx.x;       // n*128 + k
    if (t >= 1024 * 128) return;
    int n = t >> 7, k = t & 127;
    int w = n >> 8, nc = n & 255;
    const float* W = (w == 0) ? Wq : (w == 1) ? Wk : (w == 2) ? Wv : Ws;
    WT[t] = f2bf(W[k * 256 + nc]);
    if (k == 0) {
        const float* b = (w == 0) ? bq : (w == 1) ? bk : (w == 2) ? bv : bs;
        bcat[n] = b[nc];
    }
}

__global__ void prep_w2(const float* __restrict__ Wq, const float* __restrict__ Wk,
                        const float* __restrict__ Wv, const float* __restrict__ Ws,
                        const float* __restrict__ bq, const float* __restrict__ bk,
                        const float* __restrict__ bv, const float* __restrict__ bs,
                        u16* __restrict__ WT, float* __restrict__ bcat) {
    int t = blockIdx.x * 256 + threadIdx.x;       // n*256 + k
    if (t >= 896 * 256) return;
    int n = t >> 8, k = t & 255;
    float val; float bval;
    if (n < 768) {
        int w = n >> 8, nc = n & 255;
        const float* W = (w == 0) ? Wq : (w == 1) ? Wk : Wv;
        val = W[k * 256 + nc];
        bval = ((w == 0) ? bq : (w == 1) ? bk : bv)[nc];
    } else {
        val = Ws[k * 128 + (n - 768)];
        bval = bs[n - 768];
    }
    WT[t] = f2bf(val);
    if (k == 0) bcat[n] = bval;
}

// ---------------------------------------------------------------------------
// Fused MFMA GEMM: C_cat[M, Ncat] = A[M,K] @ B^T[Ncat,K]^T + bias, routed to
// up to 4 output buffers of width 256 (last one width s3).
// BM=BN=128, BK=32, 256 threads = 2x2 waves, each wave 64x64 via 4x4 frags of
// mfma_f32_16x16x32_bf16. LDS rows padded to 40 bf16 (80 B -> 2-way bank
// aliasing, free per m136).  AT = float (convert) or u16 (bf16 passthrough).
// ---------------------------------------------------------------------------
template <typename AT>
__global__ __launch_bounds__(256) void gemm_mfma(
    const AT* __restrict__ A, const u16* __restrict__ BT,
    const float* __restrict__ biascat,
    u16* __restrict__ C0, u16* __restrict__ C1,
    u16* __restrict__ C2, u16* __restrict__ C3, int s3,
    int M, int K)
{
    __shared__ u16 As[128 * 40];
    __shared__ u16 Bs[128 * 40];
    int t = threadIdx.x;
    int wid = t >> 6, lane = t & 63;
    int wm = wid >> 1, wn = wid & 1;
    int row0 = blockIdx.x * 128;
    int n0 = blockIdx.y * 128;

    f4v acc[4][4];
#pragma unroll
    for (int i = 0; i < 4; ++i)
#pragma unroll
        for (int j = 0; j < 4; ++j)
#pragma unroll
            for (int r = 0; r < 4; ++r) acc[i][j][r] = 0.f;

    for (int k0 = 0; k0 < K; k0 += 32) {
        // stage A tile (128 x 32)
        if constexpr (sizeof(AT) == 4) {
#pragma unroll
            for (int i = 0; i < 4; ++i) {
                int c = t + i * 256;            // 0..1023
                int row = c >> 3, kq = (c & 7) * 4;
                float4 d = make_float4(0.f, 0.f, 0.f, 0.f);
                if (row0 + row < M)
                    d = *(const float4*)&A[(size_t)(row0 + row) * K + k0 + kq];
                ushort4 h;
                h.x = f2bf(d.x); h.y = f2bf(d.y); h.z = f2bf(d.z); h.w = f2bf(d.w);
                *(ushort4*)&As[row * 40 + kq] = h;
            }
        } else {
#pragma unroll
            for (int i = 0; i < 2; ++i) {
                int c = t + i * 256;            // 0..511
                int row = c >> 2, kq = (c & 3) * 8;
                uint4 d = make_uint4(0u, 0u, 0u, 0u);
                if (row0 + row < M)
                    d = *(const uint4*)&A[(size_t)(row0 + row) * K + k0 + kq];
                *(uint4*)&As[row * 40 + kq] = d;
            }
        }
        // stage B^T tile (128 x 32) — rows always in range
#pragma unroll
        for (int i = 0; i < 2; ++i) {
            int c = t + i * 256;
            int row = c >> 2, kq = (c & 3) * 8;
            *(uint4*)&Bs[row * 40 + kq] = *(const uint4*)&BT[(size_t)(n0 + row) * K + k0 + kq];
        }
        __syncthreads();

        int koff = (lane >> 4) * 8;
        int mrow = wm * 64 + (lane & 15);
        int nrow = wn * 64 + (lane & 15);
        s8v af[4], bf[4];
#pragma unroll
        for (int tm = 0; tm < 4; ++tm)
            af[tm] = *(const s8v*)&As[(mrow + tm * 16) * 40 + koff];
#pragma unroll
        for (int tn = 0; tn < 4; ++tn)
            bf[tn] = *(const s8v*)&Bs[(nrow + tn * 16) * 40 + koff];
#pragma unroll
        for (int tm = 0; tm < 4; ++tm)
#pragma unroll
            for (int tn = 0; tn < 4; ++tn)
                acc[tm][tn] = __builtin_amdgcn_mfma_f32_16x16x32_bf16(
                    af[tm], bf[tn], acc[tm][tn], 0, 0, 0);
        __syncthreads();
    }

    // Epilogue: route to output buffer (buf uniform per block)
    int buf = blockIdx.y >> 1;
    u16* Cp = (buf == 0) ? C0 : (buf == 1) ? C1 : (buf == 2) ? C2 : C3;
    int stride = (buf == 3) ? s3 : 256;
    int colb = (blockIdx.y & 1) * 128;
#pragma unroll
    for (int tm = 0; tm < 4; ++tm) {
#pragma unroll
        for (int tn = 0; tn < 4; ++tn) {
            int colg = n0 + wn * 64 + tn * 16 + (lane & 15);
            int col  = colb + wn * 64 + tn * 16 + (lane & 15);
            float b = biascat[colg];
#pragma unroll
            for (int r = 0; r < 4; ++r) {
                int row = row0 + wm * 64 + tm * 16 + (lane >> 4) * 4 + r;
                if (row < M)
                    Cp[(size_t)row * stride + col] = f2bf(acc[tm][tn][r] + b);
            }
        }
    }
}

// ---------------------------------------------------------------------------
// Attention layer 1: wave per node, online softmax over incoming edges.
// ---------------------------------------------------------------------------
__global__ __launch_bounds__(256) void attn_node_l1(
    const u16* __restrict__ q, const u16* __restrict__ k,
    const u16* __restrict__ v, const float* __restrict__ We,
    const u16* __restrict__ skip, const int* __restrict__ rowptr,
    const int* __restrict__ srcs, const float* __restrict__ eas,
    u16* __restrict__ h, int N)
{
    int wave = (blockIdx.x * blockDim.x + threadIdx.x) >> 6;
    int lane = threadIdx.x & 63;
    if (wave >= N) return;
    int n = wave;
    const float scale = 0.08838834764831845f;  // 1/sqrt(128)

    ushort4 qu = *(const ushort4*)&q[(size_t)n * HC + lane * 4];
    float4 q4 = make_float4(bf2f(qu.x), bf2f(qu.y), bf2f(qu.z), bf2f(qu.w));
    float4 w4 = *(const float4*)&We[lane * 4];
    int e0 = rowptr[n], e1 = rowptr[n + 1];
    float m = -INFINITY, l = 0.f;
    float4 acc = make_float4(0.f, 0.f, 0.f, 0.f);

    for (int e = e0; e < e1; ++e) {
        int s = srcs[e];
        float a_e = eas[e];
        ushort4 ku = *(const ushort4*)&k[(size_t)s * HC + lane * 4];
        ushort4 vu = *(const ushort4*)&v[(size_t)s * HC + lane * 4];
        float kx = fmaf(a_e, w4.x, bf2f(ku.x));
        float ky = fmaf(a_e, w4.y, bf2f(ku.y));
        float kz = fmaf(a_e, w4.z, bf2f(ku.z));
        float kw = fmaf(a_e, w4.w, bf2f(ku.w));
        float part = q4.x * kx + q4.y * ky + q4.z * kz + q4.w * kw;
        part += __shfl_xor(part, 1);
        part += __shfl_xor(part, 2);
        part += __shfl_xor(part, 4);
        part += __shfl_xor(part, 8);
        part += __shfl_xor(part, 16);
        float alpha = part * scale;
        float mnew = fmaxf(m, alpha);
        float corr = __expf(m - mnew);
        float p = __expf(alpha - mnew);
        l = l * corr + p;
        acc.x = acc.x * corr + p * fmaf(a_e, w4.x, bf2f(vu.x));
        acc.y = acc.y * corr + p * fmaf(a_e, w4.y, bf2f(vu.y));
        acc.z = acc.z * corr + p * fmaf(a_e, w4.z, bf2f(vu.z));
        acc.w = acc.w * corr + p * fmaf(a_e, w4.w, bf2f(vu.w));
        m = mnew;
    }
    float inv = (l > 0.f) ? 1.f / l : 0.f;
    ushort4 su = *(const ushort4*)&skip[(size_t)n * HC + lane * 4];
    ushort4 o;
    o.x = f2bf(fmaxf(0.f, acc.x * inv + bf2f(su.x)));
    o.y = f2bf(fmaxf(0.f, acc.y * inv + bf2f(su.y)));
    o.z = f2bf(fmaxf(0.f, acc.z * inv + bf2f(su.z)));
    o.w = f2bf(fmaxf(0.f, acc.w * inv + bf2f(su.w)));
    *(ushort4*)&h[(size_t)n * HC + lane * 4] = o;
}

// ---------------------------------------------------------------------------
// Attention layer 2: mean over heads + skip (no relu). Output fp32 [N,128].
// ---------------------------------------------------------------------------
__global__ __launch_bounds__(256) void attn_node_l2(
    const u16* __restrict__ q, const u16* __restrict__ k,
    const u16* __restrict__ v, const float* __restrict__ We,
    const u16* __restrict__ skip, const int* __restrict__ rowptr,
    const int* __restrict__ srcs, const float* __restrict__ eas,
    float* __restrict__ h, int N)
{
    int wave = (blockIdx.x * blockDim.x + threadIdx.x) >> 6;
    int lane = threadIdx.x & 63;
    if (wave >= N) return;
    int n = wave;
    const float scale = 0.08838834764831845f;

    ushort4 qu = *(const ushort4*)&q[(size_t)n * HC + lane * 4];
    float4 q4 = make_float4(bf2f(qu.x), bf2f(qu.y), bf2f(qu.z), bf2f(qu.w));
    float4 w4 = *(const float4*)&We[lane * 4];
    int e0 = rowptr[n], e1 = rowptr[n + 1];
    float m = -INFINITY, l = 0.f;
    float4 acc = make_float4(0.f, 0.f, 0.f, 0.f);

    for (int e = e0; e < e1; ++e) {
        int s = srcs[e];
        float a_e = eas[e];
        ushort4 ku = *(const ushort4*)&k[(size_t)s * HC + lane * 4];
        ushort4 vu = *(const ushort4*)&v[(size_t)s * HC + lane * 4];
        float kx = fmaf(a_e, w4.x, bf2f(ku.x));
        float ky = fmaf(a_e, w4.y, bf2f(ku.y));
        float kz = fmaf(a_e, w4.z, bf2f(ku.z));
        float kw = fmaf(a_e, w4.w, bf2f(ku.w));
        float part = q4.x * kx + q4.y * ky + q4.z * kz + q4.w * kw;
        part += __shfl_xor(part, 1);
        part += __shfl_xor(part, 2);
        part += __shfl_xor(part, 4);
        part += __shfl_xor(part, 8);
        part += __shfl_xor(part, 16);
        float alpha = part * scale;
        float mnew = fmaxf(m, alpha);
        float corr = __expf(m - mnew);
        float p = __expf(alpha - mnew);
        l = l * corr + p;
        acc.x = acc.x * corr + p * fmaf(a_e, w4.x, bf2f(vu.x));
        acc.y = acc.y * corr + p * fmaf(a_e, w4.y, bf2f(vu.y));
        acc.z = acc.z * corr + p * fmaf(a_e, w4.z, bf2f(vu.z));
        acc.w = acc.w * corr + p * fmaf(a_e, w4.w, bf2f(vu.w));
        m = mnew;
    }
    float inv = (l > 0.f) ? 1.f / l : 0.f;
    float ox = acc.x * inv, oy = acc.y * inv, oz = acc.z * inv, ow = acc.w * inv;
    ox = 0.5f * (ox + __shfl_xor(ox, 32));
    oy = 0.5f * (oy + __shfl_xor(oy, 32));
    oz = 0.5f * (oz + __shfl_xor(oz, 32));
    ow = 0.5f * (ow + __shfl_xor(ow, 32));
    if (lane < 32) {
        ushort4 su = *(const ushort4*)&skip[(size_t)n * HID + lane * 4];
        float4 o;
        o.x = ox + bf2f(su.x); o.y = oy + bf2f(su.y);
        o.z = oz + bf2f(su.z); o.w = ow + bf2f(su.w);
        *(float4*)&h[(size_t)n * HID + lane * 4] = o;
    }
}

// ---------------------------------------------------------------------------
// Atomic-free pooling: batch histogram -> scan -> one wave per graph
// ---------------------------------------------------------------------------
__global__ void hist_batch_kernel(const int* __restrict__ batch, const int* __restrict__ flag,
                                  int* __restrict__ gdeg, int N) {
    int i = blockIdx.x * blockDim.x + threadIdx.x;
    if (i >= N) return;
    int f = *flag;
    int g = f ? batch[2 * (size_t)i] : batch[i];
    if ((unsigned)g < (unsigned)N_GRAPHS) atomicAdd(&gdeg[g], 1);
}

// single block, 256 threads, 10 contiguous elems/thread (2560 >= 2500)
__global__ void scan_graph_kernel(const int* __restrict__ gdeg, int* __restrict__ growptr) {
    __shared__ int sh[256];
    int t = threadIdx.x;
    int base = t * 10;
    int loc[10];
    int s = 0;
#pragma unroll
    for (int i = 0; i < 10; ++i) {
        int v = (base + i < N_GRAPHS) ? gdeg[base + i] : 0;
        loc[i] = s; s += v;
    }
    sh[t] = s;
    __syncthreads();
    for (int off = 1; off < 256; off <<= 1) {
        int val = 0;
        if (t >= off) val = sh[t - off];
        __syncthreads();
        if (t >= off) sh[t] += val;
        __syncthreads();
    }
    int excl = (t > 0) ? sh[t - 1] : 0;
#pragma unroll
    for (int i = 0; i < 10; ++i)
        if (base + i < N_GRAPHS) growptr[base + i] = excl + loc[i];
    if (t == 255) growptr[N_GRAPHS] = sh[255];
}

__global__ __launch_bounds__(256) void pool_kernel(
    const float* __restrict__ h2, const int* __restrict__ growptr,
    float* __restrict__ out) {
    int wave = (blockIdx.x * blockDim.x + threadIdx.x) >> 6;
    int lane = threadIdx.x & 63;
    if (wave >= N_GRAPHS) return;
    int r0 = growptr[wave], r1 = growptr[wave + 1];
    float sx = 0.f, sy = 0.f;
    for (int r = r0; r < r1; ++r) {
        float2 v = *(const float2*)&h2[(size_t)r * HID + lane * 2];
        sx += v.x; sy += v.y;
    }
    float inv = 1.f / fmaxf((float)(r1 - r0), 1.f);
    float2 o; o.x = sx * inv; o.y = sy * inv;
    *(float2*)&out[(size_t)wave * HID + lane * 2] = o;
}

// ---------------------------------------------------------------------------
// Launch. ws budget ~123 MB (proven-safe envelope from round 2).
// ---------------------------------------------------------------------------
extern "C" void kernel_launch(void* const* d_in, const int* in_sizes, int n_in,
                              void* d_out, int out_size, void* d_ws, size_t ws_size,
                              hipStream_t stream) {
    const float* x    = (const float*)d_in[0];
    const int*   ei   = (const int*)d_in[1];
    const int*   batch= (const int*)d_in[2];
    const float* ea   = (const float*)d_in[3];
    const float* Wq1  = (const float*)d_in[4];
    const float* bq1  = (const float*)d_in[5];
    const float* Wk1  = (const float*)d_in[6];
    const float* bk1  = (const float*)d_in[7];
    const float* Wv1  = (const float*)d_in[8];
    const float* bv1  = (const float*)d_in[9];
    const float* We1  = (const float*)d_in[10];
    const float* Ws1  = (const float*)d_in[11];
    const float* bs1  = (const float*)d_in[12];
    const float* Wq2  = (const float*)d_in[13];
    const float* bq2  = (const float*)d_in[14];
    const float* Wk2  = (const float*)d_in[15];
    const float* bk2  = (const float*)d_in[16];
    const float* Wv2  = (const float*)d_in[17];
    const float* bv2  = (const float*)d_in[18];
    const float* We2  = (const float*)d_in[19];
    const float* Ws2  = (const float*)d_in[20];
    const float* bs2  = (const float*)d_in[21];
    float* out = (float*)d_out;

    char* ws = (char*)d_ws;
    size_t off = 0;
    auto alloc = [&](size_t bytes) -> void* {
        void* p = ws + off;
        off += (bytes + 255) & ~(size_t)255;
        return p;
    };
    int*   flag_ei = (int*)alloc(4);
    int*   flag_b  = (int*)alloc(4);
    int*   deg     = (int*)alloc((size_t)N_NODES * 4);
    int*   rowptr  = (int*)alloc((size_t)(N_NODES + 1) * 4);
    int*   cursor  = (int*)alloc((size_t)N_NODES * 4);
    int*   bsums   = (int*)alloc(64 * 4);
    int*   srcs    = (int*)alloc((size_t)N_EDGES * 4);
    float* eas     = (float*)alloc((size_t)N_EDGES * 4);
    int*   gdeg    = (int*)alloc((size_t)N_GRAPHS * 4);
    int*   growptr = (int*)alloc((size_t)(N_GRAPHS + 1) * 4);
    u16*   w1T     = (u16*)alloc((size_t)1024 * 128 * 2);
    float* b1cat   = (float*)alloc(1024 * 4);
    u16*   w2T     = (u16*)alloc((size_t)896 * 256 * 2);
    float* b2cat   = (float*)alloc(896 * 4);
    u16*   B0      = (u16*)alloc((size_t)N_NODES * HC * 2);   // q1 / h1 / h2(fp32 [N,128])
    u16*   B1      = (u16*)alloc((size_t)N_NODES * HC * 2);   // k1 / q2
    u16*   B2      = (u16*)alloc((size_t)N_NODES * HC * 2);   // v1 / k2
    u16*   B3      = (u16*)alloc((size_t)N_NODES * HC * 2);   // skip1 / v2
    u16*   B4      = (u16*)alloc((size_t)N_NODES * HID * 2);  // skip2

    hipMemsetAsync(deg, 0, (size_t)N_NODES * 4, stream);
    hipMemsetAsync(gdeg, 0, (size_t)N_GRAPHS * 4, stream);

    const int E = N_EDGES;

    detect_i64_kernel<<<1, 256, 0, stream>>>(ei, 1, 1024, flag_ei);
    detect_i64_kernel<<<1, 256, 0, stream>>>(batch, 40001, 1024, flag_b);

    // CSR by dst
    hist_kernel<<<(E + 255) / 256, 256, 0, stream>>>(ei, flag_ei, deg, E);
    int nb = (N_NODES + 1023) / 1024;  // 49
    scan_local_kernel<<<nb, 256, 0, stream>>>(deg, rowptr, bsums, N_NODES);
    scan_bsums_kernel<<<1, 64, 0, stream>>>(bsums, nb, rowptr + N_NODES);
    scan_add_kernel<<<(N_NODES + 255) / 256, 256, 0, stream>>>(rowptr, bsums, cursor, N_NODES);
    scatter_kernel<<<(E + 255) / 256, 256, 0, stream>>>(ei, ea, flag_ei, cursor, srcs, eas, E);

    // graph rowptr for pooling
    hist_batch_kernel<<<(N_NODES + 255) / 256, 256, 0, stream>>>(batch, flag_b, gdeg, N_NODES);
    scan_graph_kernel<<<1, 256, 0, stream>>>(gdeg, growptr);

    // weight prep (bf16 B^T, concatenated)
    prep_w1<<<(1024 * 128 + 255) / 256, 256, 0, stream>>>(Wq1, Wk1, Wv1, Ws1, bq1, bk1, bv1, bs1, w1T, b1cat);
    prep_w2<<<(896 * 256 + 255) / 256, 256, 0, stream>>>(Wq2, Wk2, Wv2, Ws2, bq2, bk2, bv2, bs2, w2T, b2cat);

    int mgrid = (N_NODES + 127) / 128;  // 391

    // Layer 1 fused GEMM: x fp32 [50000,128] @ w1T^T -> B0..B3 (q,k,v,skip)
    gemm_mfma<float><<<dim3(mgrid, 8), 256, 0, stream>>>(
        x, w1T, b1cat, B0, B1, B2, B3, 256, N_NODES, IN_DIM);

    // h1 -> B0 (aliases q1; row-local, safe)
    attn_node_l1<<<N_NODES / 4, 256, 0, stream>>>(B0, B1, B2, We1, B3, rowptr, srcs, eas, B0, N_NODES);

    // Layer 2 fused GEMM: h1 bf16 [50000,256] @ w2T^T -> B1,B2,B3 (q,k,v) + B4 (skip, width 128)
    gemm_mfma<u16><<<dim3(mgrid, 7), 256, 0, stream>>>(
        B0, w2T, b2cat, B1, B2, B3, B4, 128, N_NODES, HC);

    // h2 (fp32 [N,128]) -> B0
    attn_node_l2<<<N_NODES / 4, 256, 0, stream>>>(B1, B2, B3, We2, B4, rowptr, srcs, eas, (float*)B0, N_NODES);

    // pooling (atomic-free)
    pool_kernel<<<(N_GRAPHS + 3) / 4, 256, 0, stream>>>((const float*)B0, growptr, out);
}

// Round 4
// 626.558 us; speedup vs baseline: 1.8068x; 1.0569x over previous
//
#include <hip/hip_runtime.h>
#include <math.h>

// Problem constants (from reference)
#define N_NODES  50000
#define N_EDGES  800000
#define N_GRAPHS 2500
#define IN_DIM   128
#define HID      128
#define HEADS    2
#define HC       256   // HEADS*HID

typedef unsigned short u16;
typedef short  s8v  __attribute__((ext_vector_type(8)));   // 8 bf16 = 4 VGPRs (MFMA A/B frag)
typedef float  f4v  __attribute__((ext_vector_type(4)));   // MFMA C/D frag

// bf16 helpers
__device__ inline float bf2f(u16 u) {
    union { unsigned int i; float f; } c; c.i = ((unsigned int)u) << 16; return c.f;
}
__device__ inline u16 f2bf(float x) {
    union { float f; unsigned int i; } c; c.f = x;
    unsigned int r = c.i + 0x7FFFu + ((c.i >> 16) & 1u);
    return (u16)(r >> 16);
}

// ---------------------------------------------------------------------------
// int64-vs-int32 autodetect (odd int32 positions are int64 high words == 0)
// block 0: edge_index (odd base 1); block 1: batch (odd base 40001)
// ---------------------------------------------------------------------------
__global__ void detect_both_kernel(const int* __restrict__ ei, const int* __restrict__ batch,
                                   int* __restrict__ flag_ei, int* __restrict__ flag_b) {
    const int* p = (blockIdx.x == 0) ? ei : batch;
    int odd_base  = (blockIdx.x == 0) ? 1 : 40001;
    int* flag     = (blockIdx.x == 0) ? flag_ei : flag_b;
    __shared__ int nz;
    if (threadIdx.x == 0) nz = 0;
    __syncthreads();
    int any = 0;
    for (int t = threadIdx.x; t < 1024; t += 256) {
        if (p[odd_base + 2 * t] != 0) any = 1;
    }
    if (any) atomicAdd(&nz, 1);
    __syncthreads();
    if (threadIdx.x == 0) *flag = (nz == 0) ? 1 : 0;
}

// ---------------------------------------------------------------------------
// Combined histogram: edge-dst degrees AND batch-graph counts in one launch
// ---------------------------------------------------------------------------
__global__ void hist_all_kernel(const int* __restrict__ ei, const int* __restrict__ batch,
                                const int* __restrict__ flag_ei, const int* __restrict__ flag_b,
                                int* __restrict__ deg, int* __restrict__ gdeg, int E, int N) {
    int i = blockIdx.x * blockDim.x + threadIdx.x;
    if (i < E) {
        int f = *flag_ei;
        int d = f ? ei[2 * ((size_t)E + i)] : ei[(size_t)E + i];
        if ((unsigned)d < (unsigned)N_NODES) atomicAdd(&deg[d], 1);
    } else if (i < E + N) {
        int j = i - E;
        int f = *flag_b;
        int g = f ? batch[2 * (size_t)j] : batch[j];
        if ((unsigned)g < (unsigned)N_GRAPHS) atomicAdd(&gdeg[g], 1);
    }
}

__global__ void scan_local_kernel(const int* __restrict__ deg, int* __restrict__ rowptr,
                                  int* __restrict__ bsums, int n) {
    __shared__ int sh[256];
    int t = threadIdx.x;
    int base = blockIdx.x * 1024 + t * 4;
    int d0 = (base + 0 < n) ? deg[base + 0] : 0;
    int d1 = (base + 1 < n) ? deg[base + 1] : 0;
    int d2 = (base + 2 < n) ? deg[base + 2] : 0;
    int d3 = (base + 3 < n) ? deg[base + 3] : 0;
    sh[t] = d0 + d1 + d2 + d3;
    __syncthreads();
    for (int off = 1; off < 256; off <<= 1) {
        int val = 0;
        if (t >= off) val = sh[t - off];
        __syncthreads();
        if (t >= off) sh[t] += val;
        __syncthreads();
    }
    int excl = (t > 0) ? sh[t - 1] : 0;
    if (t == 255) bsums[blockIdx.x] = sh[255];
    if (base + 0 < n) rowptr[base + 0] = excl;
    if (base + 1 < n) rowptr[base + 1] = excl + d0;
    if (base + 2 < n) rowptr[base + 2] = excl + d0 + d1;
    if (base + 3 < n) rowptr[base + 3] = excl + d0 + d1 + d2;
}

__global__ void scan_bsums_kernel(int* __restrict__ bsums, int nb, int* __restrict__ rowptr_last) {
    if (threadIdx.x == 0 && blockIdx.x == 0) {
        int run = 0;
        for (int i = 0; i < nb; ++i) { int v = bsums[i]; bsums[i] = run; run += v; }
        *rowptr_last = run;
    }
}

__global__ void scan_add_kernel(int* __restrict__ rowptr, const int* __restrict__ bsums,
                                int* __restrict__ cursor, int n) {
    int i = blockIdx.x * blockDim.x + threadIdx.x;
    if (i < n) {
        int r = rowptr[i] + bsums[i >> 10];
        rowptr[i] = r;
        cursor[i] = r;
    }
}

__global__ void scatter_kernel(const int* __restrict__ ei, const float* __restrict__ ea,
                               const int* __restrict__ flag, int* __restrict__ cursor,
                               int* __restrict__ srcs, float* __restrict__ eas, int E) {
    int i = blockIdx.x * blockDim.x + threadIdx.x;
    if (i >= E) return;
    int f = *flag;
    int s = f ? ei[2 * (size_t)i] : ei[i];
    int d = f ? ei[2 * ((size_t)E + i)] : ei[(size_t)E + i];
    if ((unsigned)d >= (unsigned)N_NODES) return;
    if ((unsigned)s >= (unsigned)N_NODES) s = 0;
    int p = atomicAdd(&cursor[d], 1);
    srcs[p] = s;
    eas[p]  = ea[i];
}

// single block, 256 threads, 10 contiguous elems/thread (2560 >= 2500)
__global__ void scan_graph_kernel(const int* __restrict__ gdeg, int* __restrict__ growptr) {
    __shared__ int sh[256];
    int t = threadIdx.x;
    int base = t * 10;
    int loc[10];
    int s = 0;
#pragma unroll
    for (int i = 0; i < 10; ++i) {
        int v = (base + i < N_GRAPHS) ? gdeg[base + i] : 0;
        loc[i] = s; s += v;
    }
    sh[t] = s;
    __syncthreads();
    for (int off = 1; off < 256; off <<= 1) {
        int val = 0;
        if (t >= off) val = sh[t - off];
        __syncthreads();
        if (t >= off) sh[t] += val;
        __syncthreads();
    }
    int excl = (t > 0) ? sh[t - 1] : 0;
#pragma unroll
    for (int i = 0; i < 10; ++i)
        if (base + i < N_GRAPHS) growptr[base + i] = excl + loc[i];
    if (t == 255) growptr[N_GRAPHS] = sh[255];
}

// ---------------------------------------------------------------------------
// Weight prep (merged): fp32 weights -> concatenated bf16 B^T (+ bias cat)
// layer1: [1024][128]  layer2: [896][256]
// ---------------------------------------------------------------------------
#define W1_ELEMS (1024 * 128)
#define W2_ELEMS (896 * 256)
__global__ void prep_w_kernel(
    const float* __restrict__ Wq1, const float* __restrict__ Wk1,
    const float* __restrict__ Wv1, const float* __restrict__ Ws1,
    const float* __restrict__ bq1, const float* __restrict__ bk1,
    const float* __restrict__ bv1, const float* __restrict__ bs1,
    const float* __restrict__ Wq2, const float* __restrict__ Wk2,
    const float* __restrict__ Wv2, const float* __restrict__ Ws2,
    const float* __restrict__ bq2, const float* __restrict__ bk2,
    const float* __restrict__ bv2, const float* __restrict__ bs2,
    u16* __restrict__ w1T, float* __restrict__ b1cat,
    u16* __restrict__ w2T, float* __restrict__ b2cat)
{
    int t = blockIdx.x * 256 + threadIdx.x;
    if (t < W1_ELEMS) {
        int n = t >> 7, k = t & 127;
        int w = n >> 8, nc = n & 255;
        const float* W = (w == 0) ? Wq1 : (w == 1) ? Wk1 : (w == 2) ? Wv1 : Ws1;
        w1T[t] = f2bf(W[k * 256 + nc]);
        if (k == 0) {
            const float* b = (w == 0) ? bq1 : (w == 1) ? bk1 : (w == 2) ? bv1 : bs1;
            b1cat[n] = b[nc];
        }
    } else if (t < W1_ELEMS + W2_ELEMS) {
        int t2 = t - W1_ELEMS;
        int n = t2 >> 8, k = t2 & 255;
        float val, bval;
        if (n < 768) {
            int w = n >> 8, nc = n & 255;
            const float* W = (w == 0) ? Wq2 : (w == 1) ? Wk2 : Wv2;
            val = W[k * 256 + nc];
            bval = ((w == 0) ? bq2 : (w == 1) ? bk2 : bv2)[nc];
        } else {
            val = Ws2[k * 128 + (n - 768)];
            bval = bs2[n - 768];
        }
        w2T[t2] = f2bf(val);
        if (k == 0) b2cat[n] = bval;
    }
}

// ---------------------------------------------------------------------------
// Fused MFMA GEMM (unchanged from round 3 — proven): C_cat = A @ B^T + bias,
// routed to up to 4 output buffers. BM=BN=128, BK=32, 2x2 waves, 4x4 frags.
// ---------------------------------------------------------------------------
template <typename AT>
__global__ __launch_bounds__(256) void gemm_mfma(
    const AT* __restrict__ A, const u16* __restrict__ BT,
    const float* __restrict__ biascat,
    u16* __restrict__ C0, u16* __restrict__ C1,
    u16* __restrict__ C2, u16* __restrict__ C3, int s3,
    int M, int K)
{
    __shared__ u16 As[128 * 40];
    __shared__ u16 Bs[128 * 40];
    int t = threadIdx.x;
    int wid = t >> 6, lane = t & 63;
    int wm = wid >> 1, wn = wid & 1;
    int row0 = blockIdx.x * 128;
    int n0 = blockIdx.y * 128;

    f4v acc[4][4];
#pragma unroll
    for (int i = 0; i < 4; ++i)
#pragma unroll
        for (int j = 0; j < 4; ++j)
#pragma unroll
            for (int r = 0; r < 4; ++r) acc[i][j][r] = 0.f;

    for (int k0 = 0; k0 < K; k0 += 32) {
        if constexpr (sizeof(AT) == 4) {
#pragma unroll
            for (int i = 0; i < 4; ++i) {
                int c = t + i * 256;
                int row = c >> 3, kq = (c & 7) * 4;
                float4 d = make_float4(0.f, 0.f, 0.f, 0.f);
                if (row0 + row < M)
                    d = *(const float4*)&A[(size_t)(row0 + row) * K + k0 + kq];
                ushort4 h;
                h.x = f2bf(d.x); h.y = f2bf(d.y); h.z = f2bf(d.z); h.w = f2bf(d.w);
                *(ushort4*)&As[row * 40 + kq] = h;
            }
        } else {
#pragma unroll
            for (int i = 0; i < 2; ++i) {
                int c = t + i * 256;
                int row = c >> 2, kq = (c & 3) * 8;
                uint4 d = make_uint4(0u, 0u, 0u, 0u);
                if (row0 + row < M)
                    d = *(const uint4*)&A[(size_t)(row0 + row) * K + k0 + kq];
                *(uint4*)&As[row * 40 + kq] = d;
            }
        }
#pragma unroll
        for (int i = 0; i < 2; ++i) {
            int c = t + i * 256;
            int row = c >> 2, kq = (c & 3) * 8;
            *(uint4*)&Bs[row * 40 + kq] = *(const uint4*)&BT[(size_t)(n0 + row) * K + k0 + kq];
        }
        __syncthreads();

        int koff = (lane >> 4) * 8;
        int mrow = wm * 64 + (lane & 15);
        int nrow = wn * 64 + (lane & 15);
        s8v af[4], bf[4];
#pragma unroll
        for (int tm = 0; tm < 4; ++tm)
            af[tm] = *(const s8v*)&As[(mrow + tm * 16) * 40 + koff];
#pragma unroll
        for (int tn = 0; tn < 4; ++tn)
            bf[tn] = *(const s8v*)&Bs[(nrow + tn * 16) * 40 + koff];
#pragma unroll
        for (int tm = 0; tm < 4; ++tm)
#pragma unroll
            for (int tn = 0; tn < 4; ++tn)
                acc[tm][tn] = __builtin_amdgcn_mfma_f32_16x16x32_bf16(
                    af[tm], bf[tn], acc[tm][tn], 0, 0, 0);
        __syncthreads();
    }

    int buf = blockIdx.y >> 1;
    u16* Cp = (buf == 0) ? C0 : (buf == 1) ? C1 : (buf == 2) ? C2 : C3;
    int stride = (buf == 3) ? s3 : 256;
    int colb = (blockIdx.y & 1) * 128;
#pragma unroll
    for (int tm = 0; tm < 4; ++tm) {
#pragma unroll
        for (int tn = 0; tn < 4; ++tn) {
            int colg = n0 + wn * 64 + tn * 16 + (lane & 15);
            int col  = colb + wn * 64 + tn * 16 + (lane & 15);
            float b = biascat[colg];
#pragma unroll
            for (int r = 0; r < 4; ++r) {
                int row = row0 + wm * 64 + tm * 16 + (lane >> 4) * 4 + r;
                if (row < M)
                    Cp[(size_t)row * stride + col] = f2bf(acc[tm][tn][r] + b);
            }
        }
    }
}

// ---------------------------------------------------------------------------
// Attention: wave per node, DUAL-STREAM online softmax + epsilon factoring.
//   q·(k+ae·We) = q·k + ae·(q·We)   [qw reduced once per node]
//   sum p·(v+ae·We) = sum p·v + (sum p·ae)·We   [pa folded into epilogue]
// LAYER=1: concat + skip + relu -> bf16 [N,256]
// LAYER=2: head-mean + skip -> fp32 [N,128]
// ---------------------------------------------------------------------------
template <int LAYER>
__global__ __launch_bounds__(256) void attn_node(
    const u16* __restrict__ q, const u16* __restrict__ k,
    const u16* __restrict__ v, const float* __restrict__ We,
    const u16* __restrict__ skip, const int* __restrict__ rowptr,
    const int* __restrict__ srcs, const float* __restrict__ eas,
    void* __restrict__ hout, int N)
{
    int wave = (blockIdx.x * blockDim.x + threadIdx.x) >> 6;
    int lane = threadIdx.x & 63;
    if (wave >= N) return;
    int n = wave;
    const float scale = 0.08838834764831845f;  // 1/sqrt(128)

    ushort4 qu = *(const ushort4*)&q[(size_t)n * HC + lane * 4];
    float4 q4 = make_float4(bf2f(qu.x), bf2f(qu.y), bf2f(qu.z), bf2f(qu.w));
    float4 w4 = *(const float4*)&We[lane * 4];

    // qw = q . We  (per head; reduce over the head's 32 lanes)
    float qw = q4.x * w4.x + q4.y * w4.y + q4.z * w4.z + q4.w * w4.w;
    qw += __shfl_xor(qw, 1);
    qw += __shfl_xor(qw, 2);
    qw += __shfl_xor(qw, 4);
    qw += __shfl_xor(qw, 8);
    qw += __shfl_xor(qw, 16);

    int e0 = rowptr[n], e1 = rowptr[n + 1];

    float mA = -INFINITY, lA = 0.f, paA = 0.f;
    float mB = -INFINITY, lB = 0.f, paB = 0.f;
    float4 accA = make_float4(0.f, 0.f, 0.f, 0.f);
    float4 accB = make_float4(0.f, 0.f, 0.f, 0.f);

    auto step = [&](int e, float& m, float& l, float& pa, float4& acc) {
        int s = srcs[e];
        float a_e = eas[e];
        ushort4 ku = *(const ushort4*)&k[(size_t)s * HC + lane * 4];
        ushort4 vu = *(const ushort4*)&v[(size_t)s * HC + lane * 4];
        float part = q4.x * bf2f(ku.x) + q4.y * bf2f(ku.y)
                   + q4.z * bf2f(ku.z) + q4.w * bf2f(ku.w);
        part += __shfl_xor(part, 1);
        part += __shfl_xor(part, 2);
        part += __shfl_xor(part, 4);
        part += __shfl_xor(part, 8);
        part += __shfl_xor(part, 16);
        float alpha = fmaf(a_e, qw, part) * scale;
        float mnew = fmaxf(m, alpha);
        float corr = __expf(m - mnew);   // exp(-inf)=0 on first edge
        float p = __expf(alpha - mnew);
        l = l * corr + p;
        pa = pa * corr + p * a_e;
        acc.x = fmaf(p, bf2f(vu.x), acc.x * corr);
        acc.y = fmaf(p, bf2f(vu.y), acc.y * corr);
        acc.z = fmaf(p, bf2f(vu.z), acc.z * corr);
        acc.w = fmaf(p, bf2f(vu.w), acc.w * corr);
        m = mnew;
    };

    int e = e0;
    for (; e + 1 < e1; e += 2) {
        step(e,     mA, lA, paA, accA);
        step(e + 1, mB, lB, paB, accB);
    }
    if (e < e1) step(e, mA, lA, paA, accA);

    // merge streams (guards avoid NaN from exp(-inf - -inf))
    float mst = fmaxf(mA, mB);
    float cA = (lA > 0.f) ? __expf(mA - mst) : 0.f;
    float cB = (lB > 0.f) ? __expf(mB - mst) : 0.f;
    float l = lA * cA + lB * cB;
    float pa = paA * cA + paB * cB;
    float4 acc;
    acc.x = accA.x * cA + accB.x * cB;
    acc.y = accA.y * cA + accB.y * cB;
    acc.z = accA.z * cA + accB.z * cB;
    acc.w = accA.w * cA + accB.w * cB;

    float inv = (l > 0.f) ? 1.f / l : 0.f;
    float ox = (acc.x + pa * w4.x) * inv;
    float oy = (acc.y + pa * w4.y) * inv;
    float oz = (acc.z + pa * w4.z) * inv;
    float ow = (acc.w + pa * w4.w) * inv;

    if constexpr (LAYER == 1) {
        ushort4 su = *(const ushort4*)&skip[(size_t)n * HC + lane * 4];
        ushort4 o;
        o.x = f2bf(fmaxf(0.f, ox + bf2f(su.x)));
        o.y = f2bf(fmaxf(0.f, oy + bf2f(su.y)));
        o.z = f2bf(fmaxf(0.f, oz + bf2f(su.z)));
        o.w = f2bf(fmaxf(0.f, ow + bf2f(su.w)));
        *(ushort4*)&((u16*)hout)[(size_t)n * HC + lane * 4] = o;
    } else {
        // head-mean: lane^32 holds the other head, same channel
        ox = 0.5f * (ox + __shfl_xor(ox, 32));
        oy = 0.5f * (oy + __shfl_xor(oy, 32));
        oz = 0.5f * (oz + __shfl_xor(oz, 32));
        ow = 0.5f * (ow + __shfl_xor(ow, 32));
        if (lane < 32) {
            ushort4 su = *(const ushort4*)&skip[(size_t)n * HID + lane * 4];
            float4 o;
            o.x = ox + bf2f(su.x); o.y = oy + bf2f(su.y);
            o.z = oz + bf2f(su.z); o.w = ow + bf2f(su.w);
            *(float4*)&((float*)hout)[(size_t)n * HID + lane * 4] = o;
        }
    }
}

// ---------------------------------------------------------------------------
// Atomic-free pooling: one wave per graph over dense h2 (batch is sorted)
// ---------------------------------------------------------------------------
__global__ __launch_bounds__(256) void pool_kernel(
    const float* __restrict__ h2, const int* __restrict__ growptr,
    float* __restrict__ out) {
    int wave = (blockIdx.x * blockDim.x + threadIdx.x) >> 6;
    int lane = threadIdx.x & 63;
    if (wave >= N_GRAPHS) return;
    int r0 = growptr[wave], r1 = growptr[wave + 1];
    float sx = 0.f, sy = 0.f;
    for (int r = r0; r < r1; ++r) {
        float2 v = *(const float2*)&h2[(size_t)r * HID + lane * 2];
        sx += v.x; sy += v.y;
    }
    float inv = 1.f / fmaxf((float)(r1 - r0), 1.f);
    float2 o; o.x = sx * inv; o.y = sy * inv;
    *(float2*)&out[(size_t)wave * HID + lane * 2] = o;
}

// ---------------------------------------------------------------------------
// Launch. ws budget ~123 MB (proven-safe envelope from round 2).
// ---------------------------------------------------------------------------
extern "C" void kernel_launch(void* const* d_in, const int* in_sizes, int n_in,
                              void* d_out, int out_size, void* d_ws, size_t ws_size,
                              hipStream_t stream) {
    const float* x    = (const float*)d_in[0];
    const int*   ei   = (const int*)d_in[1];
    const int*   batch= (const int*)d_in[2];
    const float* ea   = (const float*)d_in[3];
    const float* Wq1  = (const float*)d_in[4];
    const float* bq1  = (const float*)d_in[5];
    const float* Wk1  = (const float*)d_in[6];
    const float* bk1  = (const float*)d_in[7];
    const float* Wv1  = (const float*)d_in[8];
    const float* bv1  = (const float*)d_in[9];
    const float* We1  = (const float*)d_in[10];
    const float* Ws1  = (const float*)d_in[11];
    const float* bs1  = (const float*)d_in[12];
    const float* Wq2  = (const float*)d_in[13];
    const float* bq2  = (const float*)d_in[14];
    const float* Wk2  = (const float*)d_in[15];
    const float* bk2  = (const float*)d_in[16];
    const float* Wv2  = (const float*)d_in[17];
    const float* bv2  = (const float*)d_in[18];
    const float* We2  = (const float*)d_in[19];
    const float* Ws2  = (const float*)d_in[20];
    const float* bs2  = (const float*)d_in[21];
    float* out = (float*)d_out;

    char* ws = (char*)d_ws;
    size_t off = 0;
    auto alloc = [&](size_t bytes) -> void* {
        void* p = ws + off;
        off += (bytes + 255) & ~(size_t)255;
        return p;
    };
    int*   flag_ei = (int*)alloc(4);
    int*   flag_b  = (int*)alloc(4);
    int*   deg     = (int*)alloc((size_t)N_NODES * 4);
    int*   rowptr  = (int*)alloc((size_t)(N_NODES + 1) * 4);
    int*   cursor  = (int*)alloc((size_t)N_NODES * 4);
    int*   bsums   = (int*)alloc(64 * 4);
    int*   srcs    = (int*)alloc((size_t)N_EDGES * 4);
    float* eas     = (float*)alloc((size_t)N_EDGES * 4);
    int*   gdeg    = (int*)alloc((size_t)N_GRAPHS * 4);
    int*   growptr = (int*)alloc((size_t)(N_GRAPHS + 1) * 4);
    u16*   w1T     = (u16*)alloc((size_t)1024 * 128 * 2);
    float* b1cat   = (float*)alloc(1024 * 4);
    u16*   w2T     = (u16*)alloc((size_t)896 * 256 * 2);
    float* b2cat   = (float*)alloc(896 * 4);
    u16*   B0      = (u16*)alloc((size_t)N_NODES * HC * 2);   // q1 / h1 / h2(fp32 [N,128])
    u16*   B1      = (u16*)alloc((size_t)N_NODES * HC * 2);   // k1 / q2
    u16*   B2      = (u16*)alloc((size_t)N_NODES * HC * 2);   // v1 / k2
    u16*   B3      = (u16*)alloc((size_t)N_NODES * HC * 2);   // skip1 / v2
    u16*   B4      = (u16*)alloc((size_t)N_NODES * HID * 2);  // skip2

    hipMemsetAsync(deg, 0, (size_t)N_NODES * 4, stream);
    hipMemsetAsync(gdeg, 0, (size_t)N_GRAPHS * 4, stream);

    const int E = N_EDGES;

    detect_both_kernel<<<2, 256, 0, stream>>>(ei, batch, flag_ei, flag_b);

    // CSR by dst + graph histogram (merged)
    hist_all_kernel<<<(E + N_NODES + 255) / 256, 256, 0, stream>>>(
        ei, batch, flag_ei, flag_b, deg, gdeg, E, N_NODES);
    int nb = (N_NODES + 1023) / 1024;  // 49
    scan_local_kernel<<<nb, 256, 0, stream>>>(deg, rowptr, bsums, N_NODES);
    scan_bsums_kernel<<<1, 64, 0, stream>>>(bsums, nb, rowptr + N_NODES);
    scan_add_kernel<<<(N_NODES + 255) / 256, 256, 0, stream>>>(rowptr, bsums, cursor, N_NODES);
    scatter_kernel<<<(E + 255) / 256, 256, 0, stream>>>(ei, ea, flag_ei, cursor, srcs, eas, E);
    scan_graph_kernel<<<1, 256, 0, stream>>>(gdeg, growptr);

    // weight prep (merged)
    prep_w_kernel<<<(W1_ELEMS + W2_ELEMS + 255) / 256, 256, 0, stream>>>(
        Wq1, Wk1, Wv1, Ws1, bq1, bk1, bv1, bs1,
        Wq2, Wk2, Wv2, Ws2, bq2, bk2, bv2, bs2,
        w1T, b1cat, w2T, b2cat);

    int mgrid = (N_NODES + 127) / 128;  // 391

    // Layer 1 fused GEMM: x fp32 [50000,128] @ w1T^T -> B0..B3 (q,k,v,skip)
    gemm_mfma<float><<<dim3(mgrid, 8), 256, 0, stream>>>(
        x, w1T, b1cat, B0, B1, B2, B3, 256, N_NODES, IN_DIM);

    // h1 -> B0 (aliases q1; row-local, safe)
    attn_node<1><<<N_NODES / 4, 256, 0, stream>>>(B0, B1, B2, We1, B3, rowptr, srcs, eas, B0, N_NODES);

    // Layer 2 fused GEMM: h1 bf16 [50000,256] @ w2T^T -> B1,B2,B3 (q,k,v) + B4 (skip, width 128)
    gemm_mfma<u16><<<dim3(mgrid, 7), 256, 0, stream>>>(
        B0, w2T, b2cat, B1, B2, B3, B4, 128, N_NODES, HC);

    // h2 (fp32 [N,128]) -> B0
    attn_node<2><<<N_NODES / 4, 256, 0, stream>>>(B1, B2, B3, We2, B4, rowptr, srcs, eas, B0, N_NODES);

    // pooling (atomic-free)
    pool_kernel<<<(N_GRAPHS + 3) / 4, 256, 0, stream>>>((const float*)B0, growptr, out);
}

// Round 5
// 625.960 us; speedup vs baseline: 1.8085x; 1.0010x over previous
//
#include <hip/hip_runtime.h>
#include <math.h>

// Problem constants (from reference)
#define N_NODES  50000
#define N_EDGES  800000
#define N_GRAPHS 2500
#define IN_DIM   128
#define HID      128
#define HEADS    2
#define HC       256   // HEADS*HID

typedef unsigned short u16;
typedef short  s8v  __attribute__((ext_vector_type(8)));   // 8 bf16 = 4 VGPRs (MFMA A/B frag)
typedef float  f4v  __attribute__((ext_vector_type(4)));   // MFMA C/D frag

// bf16 helpers
__device__ inline float bf2f(u16 u) {
    union { unsigned int i; float f; } c; c.i = ((unsigned int)u) << 16; return c.f;
}
__device__ inline u16 f2bf(float x) {
    union { float f; unsigned int i; } c; c.f = x;
    unsigned int r = c.i + 0x7FFFu + ((c.i >> 16) & 1u);
    return (u16)(r >> 16);
}
// packed-dword bf16 extract: low half (1 inst) / high half (1 inst)
__device__ inline float bflo(unsigned int u) {
    union { unsigned int i; float f; } c; c.i = u << 16; return c.f;
}
__device__ inline float bfhi(unsigned int u) {
    union { unsigned int i; float f; } c; c.i = u & 0xffff0000u; return c.f;
}

// ---------------------------------------------------------------------------
// int64-vs-int32 autodetect (odd int32 positions are int64 high words == 0)
// ---------------------------------------------------------------------------
__global__ void detect_both_kernel(const int* __restrict__ ei, const int* __restrict__ batch,
                                   int* __restrict__ flag_ei, int* __restrict__ flag_b) {
    const int* p = (blockIdx.x == 0) ? ei : batch;
    int odd_base  = (blockIdx.x == 0) ? 1 : 40001;
    int* flag     = (blockIdx.x == 0) ? flag_ei : flag_b;
    __shared__ int nz;
    if (threadIdx.x == 0) nz = 0;
    __syncthreads();
    int any = 0;
    for (int t = threadIdx.x; t < 1024; t += 256) {
        if (p[odd_base + 2 * t] != 0) any = 1;
    }
    if (any) atomicAdd(&nz, 1);
    __syncthreads();
    if (threadIdx.x == 0) *flag = (nz == 0) ? 1 : 0;
}

// ---------------------------------------------------------------------------
// Combined histogram: edge-dst degrees AND batch-graph counts
// ---------------------------------------------------------------------------
__global__ void hist_all_kernel(const int* __restrict__ ei, const int* __restrict__ batch,
                                const int* __restrict__ flag_ei, const int* __restrict__ flag_b,
                                int* __restrict__ deg, int* __restrict__ gdeg, int E, int N) {
    int i = blockIdx.x * blockDim.x + threadIdx.x;
    if (i < E) {
        int f = *flag_ei;
        int d = f ? ei[2 * ((size_t)E + i)] : ei[(size_t)E + i];
        if ((unsigned)d < (unsigned)N_NODES) atomicAdd(&deg[d], 1);
    } else if (i < E + N) {
        int j = i - E;
        int f = *flag_b;
        int g = f ? batch[2 * (size_t)j] : batch[j];
        if ((unsigned)g < (unsigned)N_GRAPHS) atomicAdd(&gdeg[g], 1);
    }
}

__global__ void scan_local_kernel(const int* __restrict__ deg, int* __restrict__ rowptr,
                                  int* __restrict__ bsums, int n) {
    __shared__ int sh[256];
    int t = threadIdx.x;
    int base = blockIdx.x * 1024 + t * 4;
    int d0 = (base + 0 < n) ? deg[base + 0] : 0;
    int d1 = (base + 1 < n) ? deg[base + 1] : 0;
    int d2 = (base + 2 < n) ? deg[base + 2] : 0;
    int d3 = (base + 3 < n) ? deg[base + 3] : 0;
    sh[t] = d0 + d1 + d2 + d3;
    __syncthreads();
    for (int off = 1; off < 256; off <<= 1) {
        int val = 0;
        if (t >= off) val = sh[t - off];
        __syncthreads();
        if (t >= off) sh[t] += val;
        __syncthreads();
    }
    int excl = (t > 0) ? sh[t - 1] : 0;
    if (t == 255) bsums[blockIdx.x] = sh[255];
    if (base + 0 < n) rowptr[base + 0] = excl;
    if (base + 1 < n) rowptr[base + 1] = excl + d0;
    if (base + 2 < n) rowptr[base + 2] = excl + d0 + d1;
    if (base + 3 < n) rowptr[base + 3] = excl + d0 + d1 + d2;
}

__global__ void scan_bsums_kernel(int* __restrict__ bsums, int nb, int* __restrict__ rowptr_last) {
    if (threadIdx.x == 0 && blockIdx.x == 0) {
        int run = 0;
        for (int i = 0; i < nb; ++i) { int v = bsums[i]; bsums[i] = run; run += v; }
        *rowptr_last = run;
    }
}

__global__ void scan_add_kernel(int* __restrict__ rowptr, const int* __restrict__ bsums,
                                int* __restrict__ cursor, int n) {
    int i = blockIdx.x * blockDim.x + threadIdx.x;
    if (i < n) {
        int r = rowptr[i] + bsums[i >> 10];
        rowptr[i] = r;
        cursor[i] = r;
    }
}

__global__ void scatter_kernel(const int* __restrict__ ei, const float* __restrict__ ea,
                               const int* __restrict__ flag, int* __restrict__ cursor,
                               int* __restrict__ srcs, float* __restrict__ eas, int E) {
    int i = blockIdx.x * blockDim.x + threadIdx.x;
    if (i >= E) return;
    int f = *flag;
    int s = f ? ei[2 * (size_t)i] : ei[i];
    int d = f ? ei[2 * ((size_t)E + i)] : ei[(size_t)E + i];
    if ((unsigned)d >= (unsigned)N_NODES) return;
    if ((unsigned)s >= (unsigned)N_NODES) s = 0;
    int p = atomicAdd(&cursor[d], 1);
    srcs[p] = s;
    eas[p]  = ea[i];
}

// single block, 256 threads, 10 contiguous elems/thread (2560 >= 2500)
__global__ void scan_graph_kernel(const int* __restrict__ gdeg, int* __restrict__ growptr) {
    __shared__ int sh[256];
    int t = threadIdx.x;
    int base = t * 10;
    int loc[10];
    int s = 0;
#pragma unroll
    for (int i = 0; i < 10; ++i) {
        int v = (base + i < N_GRAPHS) ? gdeg[base + i] : 0;
        loc[i] = s; s += v;
    }
    sh[t] = s;
    __syncthreads();
    for (int off = 1; off < 256; off <<= 1) {
        int val = 0;
        if (t >= off) val = sh[t - off];
        __syncthreads();
        if (t >= off) sh[t] += val;
        __syncthreads();
    }
    int excl = (t > 0) ? sh[t - 1] : 0;
#pragma unroll
    for (int i = 0; i < 10; ++i)
        if (base + i < N_GRAPHS) growptr[base + i] = excl + loc[i];
    if (t == 255) growptr[N_GRAPHS] = sh[255];
}

// ---------------------------------------------------------------------------
// Weight prep (merged): fp32 weights -> concatenated bf16 B^T (+ bias cat)
// ---------------------------------------------------------------------------
#define W1_ELEMS (1024 * 128)
#define W2_ELEMS (896 * 256)
__global__ void prep_w_kernel(
    const float* __restrict__ Wq1, const float* __restrict__ Wk1,
    const float* __restrict__ Wv1, const float* __restrict__ Ws1,
    const float* __restrict__ bq1, const float* __restrict__ bk1,
    const float* __restrict__ bv1, const float* __restrict__ bs1,
    const float* __restrict__ Wq2, const float* __restrict__ Wk2,
    const float* __restrict__ Wv2, const float* __restrict__ Ws2,
    const float* __restrict__ bq2, const float* __restrict__ bk2,
    const float* __restrict__ bv2, const float* __restrict__ bs2,
    u16* __restrict__ w1T, float* __restrict__ b1cat,
    u16* __restrict__ w2T, float* __restrict__ b2cat)
{
    int t = blockIdx.x * 256 + threadIdx.x;
    if (t < W1_ELEMS) {
        int n = t >> 7, k = t & 127;
        int w = n >> 8, nc = n & 255;
        const float* W = (w == 0) ? Wq1 : (w == 1) ? Wk1 : (w == 2) ? Wv1 : Ws1;
        w1T[t] = f2bf(W[k * 256 + nc]);
        if (k == 0) {
            const float* b = (w == 0) ? bq1 : (w == 1) ? bk1 : (w == 2) ? bv1 : bs1;
            b1cat[n] = b[nc];
        }
    } else if (t < W1_ELEMS + W2_ELEMS) {
        int t2 = t - W1_ELEMS;
        int n = t2 >> 8, k = t2 & 255;
        float val, bval;
        if (n < 768) {
            int w = n >> 8, nc = n & 255;
            const float* W = (w == 0) ? Wq2 : (w == 1) ? Wk2 : Wv2;
            val = W[k * 256 + nc];
            bval = ((w == 0) ? bq2 : (w == 1) ? bk2 : bv2)[nc];
        } else {
            val = Ws2[k * 128 + (n - 768)];
            bval = bs2[n - 768];
        }
        w2T[t2] = f2bf(val);
        if (k == 0) b2cat[n] = bval;
    }
}

// ---------------------------------------------------------------------------
// Fused MFMA GEMM: C_cat = A @ B^T + bias, routed to up to 4 output buffers,
// each with its own base pointer and row stride (enables k|v interleaved KV).
// BM=BN=128, BK=32, 2x2 waves, 4x4 frags of mfma_f32_16x16x32_bf16.
// ---------------------------------------------------------------------------
template <typename AT>
__global__ __launch_bounds__(256) void gemm_mfma(
    const AT* __restrict__ A, const u16* __restrict__ BT,
    const float* __restrict__ biascat,
    u16* __restrict__ C0, u16* __restrict__ C1,
    u16* __restrict__ C2, u16* __restrict__ C3,
    int s0, int s1, int s2, int s3,
    int M, int K)
{
    __shared__ u16 As[128 * 40];
    __shared__ u16 Bs[128 * 40];
    int t = threadIdx.x;
    int wid = t >> 6, lane = t & 63;
    int wm = wid >> 1, wn = wid & 1;
    int row0 = blockIdx.x * 128;
    int n0 = blockIdx.y * 128;

    f4v acc[4][4];
#pragma unroll
    for (int i = 0; i < 4; ++i)
#pragma unroll
        for (int j = 0; j < 4; ++j)
#pragma unroll
            for (int r = 0; r < 4; ++r) acc[i][j][r] = 0.f;

    for (int k0 = 0; k0 < K; k0 += 32) {
        if constexpr (sizeof(AT) == 4) {
#pragma unroll
            for (int i = 0; i < 4; ++i) {
                int c = t + i * 256;
                int row = c >> 3, kq = (c & 7) * 4;
                float4 d = make_float4(0.f, 0.f, 0.f, 0.f);
                if (row0 + row < M)
                    d = *(const float4*)&A[(size_t)(row0 + row) * K + k0 + kq];
                ushort4 h;
                h.x = f2bf(d.x); h.y = f2bf(d.y); h.z = f2bf(d.z); h.w = f2bf(d.w);
                *(ushort4*)&As[row * 40 + kq] = h;
            }
        } else {
#pragma unroll
            for (int i = 0; i < 2; ++i) {
                int c = t + i * 256;
                int row = c >> 2, kq = (c & 3) * 8;
                uint4 d = make_uint4(0u, 0u, 0u, 0u);
                if (row0 + row < M)
                    d = *(const uint4*)&A[(size_t)(row0 + row) * K + k0 + kq];
                *(uint4*)&As[row * 40 + kq] = d;
            }
        }
#pragma unroll
        for (int i = 0; i < 2; ++i) {
            int c = t + i * 256;
            int row = c >> 2, kq = (c & 3) * 8;
            *(uint4*)&Bs[row * 40 + kq] = *(const uint4*)&BT[(size_t)(n0 + row) * K + k0 + kq];
        }
        __syncthreads();

        int koff = (lane >> 4) * 8;
        int mrow = wm * 64 + (lane & 15);
        int nrow = wn * 64 + (lane & 15);
        s8v af[4], bf[4];
#pragma unroll
        for (int tm = 0; tm < 4; ++tm)
            af[tm] = *(const s8v*)&As[(mrow + tm * 16) * 40 + koff];
#pragma unroll
        for (int tn = 0; tn < 4; ++tn)
            bf[tn] = *(const s8v*)&Bs[(nrow + tn * 16) * 40 + koff];
#pragma unroll
        for (int tm = 0; tm < 4; ++tm)
#pragma unroll
            for (int tn = 0; tn < 4; ++tn)
                acc[tm][tn] = __builtin_amdgcn_mfma_f32_16x16x32_bf16(
                    af[tm], bf[tn], acc[tm][tn], 0, 0, 0);
        __syncthreads();
    }

    int buf = blockIdx.y >> 1;
    u16* Cp = (buf == 0) ? C0 : (buf == 1) ? C1 : (buf == 2) ? C2 : C3;
    int stride = (buf == 0) ? s0 : (buf == 1) ? s1 : (buf == 2) ? s2 : s3;
    int colb = (blockIdx.y & 1) * 128;
#pragma unroll
    for (int tm = 0; tm < 4; ++tm) {
#pragma unroll
        for (int tn = 0; tn < 4; ++tn) {
            int colg = n0 + wn * 64 + tn * 16 + (lane & 15);
            int col  = colb + wn * 64 + tn * 16 + (lane & 15);
            float b = biascat[colg];
#pragma unroll
            for (int r = 0; r < 4; ++r) {
                int row = row0 + wm * 64 + tm * 16 + (lane >> 4) * 4 + r;
                if (row < M)
                    Cp[(size_t)row * stride + col] = f2bf(acc[tm][tn][r] + b);
            }
        }
    }
}

// ---------------------------------------------------------------------------
// Attention: wave per node, 2 EDGES PER STEP (lanes 0-31 = edge A, 32-63 =
// edge B), each lane owns 8 contiguous cols (16B gathers). kv interleaved
// [N][512]: k = cols 0..255, v = cols 256..511 (one address per edge).
// Epsilon factoring: alpha = (q.k + ae*(q.We))*scale; v-side folded via pa.
// LAYER=1: concat + skip + relu -> bf16 [N,256]
// LAYER=2: head-mean + skip -> fp32 [N,128]
// ---------------------------------------------------------------------------
template <int LAYER>
__global__ __launch_bounds__(256) void attn_node(
    const u16* __restrict__ q, const u16* __restrict__ kv,
    const float* __restrict__ We, const u16* __restrict__ skip,
    const int* __restrict__ rowptr, const int* __restrict__ srcs,
    const float* __restrict__ eas, void* __restrict__ hout, int N)
{
    int wave = (blockIdx.x * blockDim.x + threadIdx.x) >> 6;
    int lane = threadIdx.x & 63;
    if (wave >= N) return;
    int n = wave;
    int half = lane >> 5;        // 0: edge stream A, 1: edge stream B
    int cl   = lane & 31;        // col-lane: owns cols 8*cl .. 8*cl+7
    const float scale = 0.08838834764831845f;  // 1/sqrt(128)
    const float NEG = -1e30f;

    // q cols 8cl..8cl+7 (both halves load the same row — broadcast from cache)
    uint4 qd = *(const uint4*)&q[(size_t)n * HC + cl * 8];
    float qf[8];
    qf[0] = bflo(qd.x); qf[1] = bfhi(qd.x);
    qf[2] = bflo(qd.y); qf[3] = bfhi(qd.y);
    qf[4] = bflo(qd.z); qf[5] = bfhi(qd.z);
    qf[6] = bflo(qd.w); qf[7] = bfhi(qd.w);
    float4 wlo = *(const float4*)&We[cl * 8];
    float4 whi = *(const float4*)&We[cl * 8 + 4];
    float wf[8] = { wlo.x, wlo.y, wlo.z, wlo.w, whi.x, whi.y, whi.z, whi.w };

    // qw = q . We per head (reduce over the head's 16 col-lanes)
    float qw = qf[0]*wf[0] + qf[1]*wf[1] + qf[2]*wf[2] + qf[3]*wf[3]
             + qf[4]*wf[4] + qf[5]*wf[5] + qf[6]*wf[6] + qf[7]*wf[7];
    qw += __shfl_xor(qw, 1);
    qw += __shfl_xor(qw, 2);
    qw += __shfl_xor(qw, 4);
    qw += __shfl_xor(qw, 8);

    int e0 = rowptr[n], e1 = rowptr[n + 1];
    float m = NEG, l = 0.f, pa = 0.f;
    float acc[8];
#pragma unroll
    for (int i = 0; i < 8; ++i) acc[i] = 0.f;

    int steps = (e1 - e0 + 1) >> 1;
    for (int st = 0; st < steps; ++st) {
        int e = e0 + 2 * st + half;
        bool act = (e < e1);
        int idx = act ? e : e0;          // e0 < E whenever steps > 0
        int s = srcs[idx];
        float a_e = eas[idx];
        const u16* base = kv + (size_t)s * 512 + cl * 8;
        uint4 kd = *(const uint4*)base;          // k cols 8cl..+7
        uint4 vd = *(const uint4*)(base + 256);  // v cols 8cl..+7

        float d = qf[0] * bflo(kd.x);
        d = fmaf(qf[1], bfhi(kd.x), d);
        d = fmaf(qf[2], bflo(kd.y), d);
        d = fmaf(qf[3], bfhi(kd.y), d);
        d = fmaf(qf[4], bflo(kd.z), d);
        d = fmaf(qf[5], bfhi(kd.z), d);
        d = fmaf(qf[6], bflo(kd.w), d);
        d = fmaf(qf[7], bfhi(kd.w), d);
        d += __shfl_xor(d, 1);
        d += __shfl_xor(d, 2);
        d += __shfl_xor(d, 4);
        d += __shfl_xor(d, 8);

        float alpha = act ? fmaf(a_e, qw, d) * scale : NEG;
        float mnew = fmaxf(m, alpha);
        float corr = __expf(m - mnew);           // finite args: no NaN
        float p = __expf(alpha - mnew);
        p = act ? p : 0.f;
        l = fmaf(l, corr, p);
        pa = fmaf(pa, corr, p * a_e);
        acc[0] = fmaf(p, bflo(vd.x), acc[0] * corr);
        acc[1] = fmaf(p, bfhi(vd.x), acc[1] * corr);
        acc[2] = fmaf(p, bflo(vd.y), acc[2] * corr);
        acc[3] = fmaf(p, bfhi(vd.y), acc[3] * corr);
        acc[4] = fmaf(p, bflo(vd.z), acc[4] * corr);
        acc[5] = fmaf(p, bfhi(vd.z), acc[5] * corr);
        acc[6] = fmaf(p, bflo(vd.w), acc[6] * corr);
        acc[7] = fmaf(p, bfhi(vd.w), acc[7] * corr);
        m = mnew;
    }

    // merge streams A (lanes 0-31) and B (lanes 32-63): exchange via xor 32
    float mo = __shfl_xor(m, 32);
    float lo = __shfl_xor(l, 32);
    float pao = __shfl_xor(pa, 32);
    float mst = fmaxf(m, mo);
    float cS = __expf(m - mst);      // both NEG -> exp(0)=1, but l=0 anyway
    float cO = __expf(mo - mst);
    l = l * cS + lo * cO;
    pa = pa * cS + pao * cO;
#pragma unroll
    for (int i = 0; i < 8; ++i) {
        float ao = __shfl_xor(acc[i], 32);
        acc[i] = acc[i] * cS + ao * cO;
    }

    float inv = (l > 0.f) ? 1.f / l : 0.f;
    float o[8];
#pragma unroll
    for (int i = 0; i < 8; ++i) o[i] = fmaf(pa, wf[i], acc[i]) * inv;

    if constexpr (LAYER == 1) {
        if (half == 0) {
            uint4 sd = *(const uint4*)&skip[(size_t)n * HC + cl * 8];
            float sf[8];
            sf[0] = bflo(sd.x); sf[1] = bfhi(sd.x);
            sf[2] = bflo(sd.y); sf[3] = bfhi(sd.y);
            sf[4] = bflo(sd.z); sf[5] = bfhi(sd.z);
            sf[6] = bflo(sd.w); sf[7] = bfhi(sd.w);
            ushort4 o4a, o4b;
            o4a.x = f2bf(fmaxf(0.f, o[0] + sf[0]));
            o4a.y = f2bf(fmaxf(0.f, o[1] + sf[1]));
            o4a.z = f2bf(fmaxf(0.f, o[2] + sf[2]));
            o4a.w = f2bf(fmaxf(0.f, o[3] + sf[3]));
            o4b.x = f2bf(fmaxf(0.f, o[4] + sf[4]));
            o4b.y = f2bf(fmaxf(0.f, o[5] + sf[5]));
            o4b.z = f2bf(fmaxf(0.f, o[6] + sf[6]));
            o4b.w = f2bf(fmaxf(0.f, o[7] + sf[7]));
            u16* hp = (u16*)hout + (size_t)n * HC + cl * 8;
            *(ushort4*)hp = o4a;
            *(ushort4*)(hp + 4) = o4b;
        }
    } else {
        // head-mean: col-lane cl (head0) pairs with cl^16 (head1), same cols
#pragma unroll
        for (int i = 0; i < 8; ++i) {
            float t2 = __shfl_xor(o[i], 16);
            o[i] = 0.5f * (o[i] + t2);
        }
        if (lane < 16) {
            uint4 sd = *(const uint4*)&skip[(size_t)n * HID + lane * 8];
            float sf[8];
            sf[0] = bflo(sd.x); sf[1] = bfhi(sd.x);
            sf[2] = bflo(sd.y); sf[3] = bfhi(sd.y);
            sf[4] = bflo(sd.z); sf[5] = bfhi(sd.z);
            sf[6] = bflo(sd.w); sf[7] = bfhi(sd.w);
            float* hp = (float*)hout + (size_t)n * HID + lane * 8;
            float4 oa, ob;
            oa.x = o[0] + sf[0]; oa.y = o[1] + sf[1];
            oa.z = o[2] + sf[2]; oa.w = o[3] + sf[3];
            ob.x = o[4] + sf[4]; ob.y = o[5] + sf[5];
            ob.z = o[6] + sf[6]; ob.w = o[7] + sf[7];
            *(float4*)hp = oa;
            *(float4*)(hp + 4) = ob;
        }
    }
}

// ---------------------------------------------------------------------------
// Atomic-free pooling: one wave per graph over dense h2 (batch is sorted)
// ---------------------------------------------------------------------------
__global__ __launch_bounds__(256) void pool_kernel(
    const float* __restrict__ h2, const int* __restrict__ growptr,
    float* __restrict__ out) {
    int wave = (blockIdx.x * blockDim.x + threadIdx.x) >> 6;
    int lane = threadIdx.x & 63;
    if (wave >= N_GRAPHS) return;
    int r0 = growptr[wave], r1 = growptr[wave + 1];
    float sx = 0.f, sy = 0.f;
    for (int r = r0; r < r1; ++r) {
        float2 v = *(const float2*)&h2[(size_t)r * HID + lane * 2];
        sx += v.x; sy += v.y;
    }
    float inv = 1.f / fmaxf((float)(r1 - r0), 1.f);
    float2 o; o.x = sx * inv; o.y = sy * inv;
    *(float2*)&out[(size_t)wave * HID + lane * 2] = o;
}

// ---------------------------------------------------------------------------
// Launch. ws ~123 MB (proven-safe envelope). KV = interleaved k|v [N,512].
// ---------------------------------------------------------------------------
extern "C" void kernel_launch(void* const* d_in, const int* in_sizes, int n_in,
                              void* d_out, int out_size, void* d_ws, size_t ws_size,
                              hipStream_t stream) {
    const float* x    = (const float*)d_in[0];
    const int*   ei   = (const int*)d_in[1];
    const int*   batch= (const int*)d_in[2];
    const float* ea   = (const float*)d_in[3];
    const float* Wq1  = (const float*)d_in[4];
    const float* bq1  = (const float*)d_in[5];
    const float* Wk1  = (const float*)d_in[6];
    const float* bk1  = (const float*)d_in[7];
    const float* Wv1  = (const float*)d_in[8];
    const float* bv1  = (const float*)d_in[9];
    const float* We1  = (const float*)d_in[10];
    const float* Ws1  = (const float*)d_in[11];
    const float* bs1  = (const float*)d_in[12];
    const float* Wq2  = (const float*)d_in[13];
    const float* bq2  = (const float*)d_in[14];
    const float* Wk2  = (const float*)d_in[15];
    const float* bk2  = (const float*)d_in[16];
    const float* Wv2  = (const float*)d_in[17];
    const float* bv2  = (const float*)d_in[18];
    const float* We2  = (const float*)d_in[19];
    const float* Ws2  = (const float*)d_in[20];
    const float* bs2  = (const float*)d_in[21];
    float* out = (float*)d_out;

    char* ws = (char*)d_ws;
    size_t off = 0;
    auto alloc = [&](size_t bytes) -> void* {
        void* p = ws + off;
        off += (bytes + 255) & ~(size_t)255;
        return p;
    };
    int*   flag_ei = (int*)alloc(4);
    int*   flag_b  = (int*)alloc(4);
    int*   deg     = (int*)alloc((size_t)N_NODES * 4);
    int*   rowptr  = (int*)alloc((size_t)(N_NODES + 1) * 4);
    int*   cursor  = (int*)alloc((size_t)N_NODES * 4);
    int*   bsums   = (int*)alloc(64 * 4);
    int*   srcs    = (int*)alloc((size_t)N_EDGES * 4);
    float* eas     = (float*)alloc((size_t)N_EDGES * 4);
    int*   gdeg    = (int*)alloc((size_t)N_GRAPHS * 4);
    int*   growptr = (int*)alloc((size_t)(N_GRAPHS + 1) * 4);
    u16*   w1T     = (u16*)alloc((size_t)1024 * 128 * 2);
    float* b1cat   = (float*)alloc(1024 * 4);
    u16*   w2T     = (u16*)alloc((size_t)896 * 256 * 2);
    float* b2cat   = (float*)alloc(896 * 4);
    u16*   B0      = (u16*)alloc((size_t)N_NODES * HC * 2);   // q1 / h1 / h2(fp32 [N,128])
    u16*   B1      = (u16*)alloc((size_t)N_NODES * HC * 2);   // skip1 / q2
    u16*   KV      = (u16*)alloc((size_t)N_NODES * 512 * 2);  // k|v interleaved (both layers)
    u16*   B4      = (u16*)alloc((size_t)N_NODES * HID * 2);  // skip2

    hipMemsetAsync(deg, 0, (size_t)N_NODES * 4, stream);
    hipMemsetAsync(gdeg, 0, (size_t)N_GRAPHS * 4, stream);

    const int E = N_EDGES;

    detect_both_kernel<<<2, 256, 0, stream>>>(ei, batch, flag_ei, flag_b);

    hist_all_kernel<<<(E + N_NODES + 255) / 256, 256, 0, stream>>>(
        ei, batch, flag_ei, flag_b, deg, gdeg, E, N_NODES);
    int nb = (N_NODES + 1023) / 1024;  // 49
    scan_local_kernel<<<nb, 256, 0, stream>>>(deg, rowptr, bsums, N_NODES);
    scan_bsums_kernel<<<1, 64, 0, stream>>>(bsums, nb, rowptr + N_NODES);
    scan_add_kernel<<<(N_NODES + 255) / 256, 256, 0, stream>>>(rowptr, bsums, cursor, N_NODES);
    scatter_kernel<<<(E + 255) / 256, 256, 0, stream>>>(ei, ea, flag_ei, cursor, srcs, eas, E);
    scan_graph_kernel<<<1, 256, 0, stream>>>(gdeg, growptr);

    prep_w_kernel<<<(W1_ELEMS + W2_ELEMS + 255) / 256, 256, 0, stream>>>(
        Wq1, Wk1, Wv1, Ws1, bq1, bk1, bv1, bs1,
        Wq2, Wk2, Wv2, Ws2, bq2, bk2, bv2, bs2,
        w1T, b1cat, w2T, b2cat);

    int mgrid = (N_NODES + 127) / 128;  // 391

    // Layer 1 fused GEMM: q->B0(256), k->KV cols 0-255(512), v->KV cols 256-511(512), skip->B1(256)
    gemm_mfma<float><<<dim3(mgrid, 8), 256, 0, stream>>>(
        x, w1T, b1cat, B0, KV, KV + 256, B1, 256, 512, 512, 256, N_NODES, IN_DIM);

    // h1 -> B0 (aliases q1; row-local, safe)
    attn_node<1><<<N_NODES / 4, 256, 0, stream>>>(B0, KV, We1, B1, rowptr, srcs, eas, B0, N_NODES);

    // Layer 2 fused GEMM: q2->B1(256), k2->KV(512), v2->KV+256(512), skip2->B4(128)
    gemm_mfma<u16><<<dim3(mgrid, 7), 256, 0, stream>>>(
        B0, w2T, b2cat, B1, KV, KV + 256, B4, 256, 512, 512, 128, N_NODES, HC);

    // h2 (fp32 [N,128]) -> B0
    attn_node<2><<<N_NODES / 4, 256, 0, stream>>>(B1, KV, We2, B4, rowptr, srcs, eas, B0, N_NODES);

    pool_kernel<<<(N_GRAPHS + 3) / 4, 256, 0, stream>>>((const float*)B0, growptr, out);
}

// Round 6
// 620.647 us; speedup vs baseline: 1.8240x; 1.0086x over previous
//
#include <hip/hip_runtime.h>
#include <math.h>

// Problem constants (from reference)
#define N_NODES  50000
#define N_EDGES  800000
#define N_GRAPHS 2500
#define IN_DIM   128
#define HID      128
#define HEADS    2
#define HC       256   // HEADS*HID

typedef unsigned short u16;
typedef short  s8v  __attribute__((ext_vector_type(8)));   // 8 bf16 = 4 VGPRs (MFMA A/B frag)
typedef float  f4v  __attribute__((ext_vector_type(4)));   // MFMA C/D frag

// bf16 helpers
__device__ inline float bf2f(u16 u) {
    union { unsigned int i; float f; } c; c.i = ((unsigned int)u) << 16; return c.f;
}
__device__ inline u16 f2bf(float x) {
    union { float f; unsigned int i; } c; c.f = x;
    unsigned int r = c.i + 0x7FFFu + ((c.i >> 16) & 1u);
    return (u16)(r >> 16);
}
// packed-dword bf16 extract
__device__ inline float bflo(unsigned int u) {
    union { unsigned int i; float f; } c; c.i = u << 16; return c.f;
}
__device__ inline float bfhi(unsigned int u) {
    union { unsigned int i; float f; } c; c.i = u & 0xffff0000u; return c.f;
}

// ---------------------------------------------------------------------------
// int64-vs-int32 autodetect (odd int32 positions are int64 high words == 0)
// ---------------------------------------------------------------------------
__global__ void detect_both_kernel(const int* __restrict__ ei, const int* __restrict__ batch,
                                   int* __restrict__ flag_ei, int* __restrict__ flag_b) {
    const int* p = (blockIdx.x == 0) ? ei : batch;
    int odd_base  = (blockIdx.x == 0) ? 1 : 40001;
    int* flag     = (blockIdx.x == 0) ? flag_ei : flag_b;
    __shared__ int nz;
    if (threadIdx.x == 0) nz = 0;
    __syncthreads();
    int any = 0;
    for (int t = threadIdx.x; t < 1024; t += 256) {
        if (p[odd_base + 2 * t] != 0) any = 1;
    }
    if (any) atomicAdd(&nz, 1);
    __syncthreads();
    if (threadIdx.x == 0) *flag = (nz == 0) ? 1 : 0;
}

// ---------------------------------------------------------------------------
// Combined histogram: edge-dst degrees AND batch-graph counts
// ---------------------------------------------------------------------------
__global__ void hist_all_kernel(const int* __restrict__ ei, const int* __restrict__ batch,
                                const int* __restrict__ flag_ei, const int* __restrict__ flag_b,
                                int* __restrict__ deg, int* __restrict__ gdeg, int E, int N) {
    int i = blockIdx.x * blockDim.x + threadIdx.x;
    if (i < E) {
        int f = *flag_ei;
        int d = f ? ei[2 * ((size_t)E + i)] : ei[(size_t)E + i];
        if ((unsigned)d < (unsigned)N_NODES) atomicAdd(&deg[d], 1);
    } else if (i < E + N) {
        int j = i - E;
        int f = *flag_b;
        int g = f ? batch[2 * (size_t)j] : batch[j];
        if ((unsigned)g < (unsigned)N_GRAPHS) atomicAdd(&gdeg[g], 1);
    }
}

__global__ void scan_local_kernel(const int* __restrict__ deg, int* __restrict__ rowptr,
                                  int* __restrict__ bsums, int n) {
    __shared__ int sh[256];
    int t = threadIdx.x;
    int base = blockIdx.x * 1024 + t * 4;
    int d0 = (base + 0 < n) ? deg[base + 0] : 0;
    int d1 = (base + 1 < n) ? deg[base + 1] : 0;
    int d2 = (base + 2 < n) ? deg[base + 2] : 0;
    int d3 = (base + 3 < n) ? deg[base + 3] : 0;
    sh[t] = d0 + d1 + d2 + d3;
    __syncthreads();
    for (int off = 1; off < 256; off <<= 1) {
        int val = 0;
        if (t >= off) val = sh[t - off];
        __syncthreads();
        if (t >= off) sh[t] += val;
        __syncthreads();
    }
    int excl = (t > 0) ? sh[t - 1] : 0;
    if (t == 255) bsums[blockIdx.x] = sh[255];
    if (base + 0 < n) rowptr[base + 0] = excl;
    if (base + 1 < n) rowptr[base + 1] = excl + d0;
    if (base + 2 < n) rowptr[base + 2] = excl + d0 + d1;
    if (base + 3 < n) rowptr[base + 3] = excl + d0 + d1 + d2;
}

// wave-parallel exclusive scan of nb (<=64) block sums; writes total
__global__ void scan_bsums_kernel(int* __restrict__ bsums, int nb, int* __restrict__ rowptr_last) {
    int lane = threadIdx.x;          // 64 threads
    int v = (lane < nb) ? bsums[lane] : 0;
    int incl = v;
    for (int off = 1; off < 64; off <<= 1) {
        int u = __shfl_up(incl, off);
        if (lane >= off) incl += u;
    }
    if (lane < nb) bsums[lane] = incl - v;
    if (lane == 63) *rowptr_last = incl;
}

__global__ void scan_add_kernel(int* __restrict__ rowptr, const int* __restrict__ bsums,
                                int* __restrict__ cursor, int n) {
    int i = blockIdx.x * blockDim.x + threadIdx.x;
    if (i < n) {
        int r = rowptr[i] + bsums[i >> 10];
        rowptr[i] = r;
        cursor[i] = r;
    }
}

// packed (src, ea-bits) records: one 8B scattered store per edge
__global__ void scatter_kernel(const int* __restrict__ ei, const float* __restrict__ ea,
                               const int* __restrict__ flag, int* __restrict__ cursor,
                               int2* __restrict__ edges, int E) {
    int i = blockIdx.x * blockDim.x + threadIdx.x;
    if (i >= E) return;
    int f = *flag;
    int s = f ? ei[2 * (size_t)i] : ei[i];
    int d = f ? ei[2 * ((size_t)E + i)] : ei[(size_t)E + i];
    if ((unsigned)d >= (unsigned)N_NODES) return;
    if ((unsigned)s >= (unsigned)N_NODES) s = 0;
    int p = atomicAdd(&cursor[d], 1);
    int2 rec; rec.x = s; rec.y = __float_as_int(ea[i]);
    edges[p] = rec;
}

// single block, 256 threads, 10 contiguous elems/thread (2560 >= 2500)
__global__ void scan_graph_kernel(const int* __restrict__ gdeg, int* __restrict__ growptr) {
    __shared__ int sh[256];
    int t = threadIdx.x;
    int base = t * 10;
    int loc[10];
    int s = 0;
#pragma unroll
    for (int i = 0; i < 10; ++i) {
        int v = (base + i < N_GRAPHS) ? gdeg[base + i] : 0;
        loc[i] = s; s += v;
    }
    sh[t] = s;
    __syncthreads();
    for (int off = 1; off < 256; off <<= 1) {
        int val = 0;
        if (t >= off) val = sh[t - off];
        __syncthreads();
        if (t >= off) sh[t] += val;
        __syncthreads();
    }
    int excl = (t > 0) ? sh[t - 1] : 0;
#pragma unroll
    for (int i = 0; i < 10; ++i)
        if (base + i < N_GRAPHS) growptr[base + i] = excl + loc[i];
    if (t == 255) growptr[N_GRAPHS] = sh[255];
}

// ---------------------------------------------------------------------------
// Weight prep (merged): fp32 weights -> concatenated bf16 B^T (+ bias cat)
// ---------------------------------------------------------------------------
#define W1_ELEMS (1024 * 128)
#define W2_ELEMS (896 * 256)
__global__ void prep_w_kernel(
    const float* __restrict__ Wq1, const float* __restrict__ Wk1,
    const float* __restrict__ Wv1, const float* __restrict__ Ws1,
    const float* __restrict__ bq1, const float* __restrict__ bk1,
    const float* __restrict__ bv1, const float* __restrict__ bs1,
    const float* __restrict__ Wq2, const float* __restrict__ Wk2,
    const float* __restrict__ Wv2, const float* __restrict__ Ws2,
    const float* __restrict__ bq2, const float* __restrict__ bk2,
    const float* __restrict__ bv2, const float* __restrict__ bs2,
    u16* __restrict__ w1T, float* __restrict__ b1cat,
    u16* __restrict__ w2T, float* __restrict__ b2cat)
{
    int t = blockIdx.x * 256 + threadIdx.x;
    if (t < W1_ELEMS) {
        int n = t >> 7, k = t & 127;
        int w = n >> 8, nc = n & 255;
        const float* W = (w == 0) ? Wq1 : (w == 1) ? Wk1 : (w == 2) ? Wv1 : Ws1;
        w1T[t] = f2bf(W[k * 256 + nc]);
        if (k == 0) {
            const float* b = (w == 0) ? bq1 : (w == 1) ? bk1 : (w == 2) ? bv1 : bs1;
            b1cat[n] = b[nc];
        }
    } else if (t < W1_ELEMS + W2_ELEMS) {
        int t2 = t - W1_ELEMS;
        int n = t2 >> 8, k = t2 & 255;
        float val, bval;
        if (n < 768) {
            int w = n >> 8, nc = n & 255;
            const float* W = (w == 0) ? Wq2 : (w == 1) ? Wk2 : Wv2;
            val = W[k * 256 + nc];
            bval = ((w == 0) ? bq2 : (w == 1) ? bk2 : bv2)[nc];
        } else {
            val = Ws2[k * 128 + (n - 768)];
            bval = bs2[n - 768];
        }
        w2T[t2] = f2bf(val);
        if (k == 0) b2cat[n] = bval;
    }
}

// ---------------------------------------------------------------------------
// A-slab-resident MFMA GEMM. 1-D grid over 128-row slabs. The block stages its
// entire A slab (128 x K, bf16, padded rows) into LDS ONCE, then loops the NT
// 128-col B^T tiles, staging only the 8 KB L2-hot B tile per 32-K chunk.
// A global traffic: read once (was x NT). Row pads give 2-way bank aliasing
// (free, m136). Epilogue routes each n-tile to one of 4 buffers w/ stride.
// ---------------------------------------------------------------------------
template <typename AT, int KDIM, int NT, int APAD>
__global__ __launch_bounds__(256) void gemm_slab(
    const AT* __restrict__ A, const u16* __restrict__ BT,
    const float* __restrict__ biascat,
    u16* __restrict__ C0, u16* __restrict__ C1,
    u16* __restrict__ C2, u16* __restrict__ C3,
    int s0, int s1, int s2, int s3, int M)
{
    constexpr int AROW = KDIM + APAD;           // u16 elems per LDS A row
    __shared__ u16 As[128 * AROW];
    __shared__ u16 Bs[128 * 40];
    int t = threadIdx.x;
    int wid = t >> 6, lane = t & 63;
    int wm = wid >> 1, wn = wid & 1;
    int row0 = blockIdx.x * 128;

    // ---- stage A slab once ----
    if constexpr (sizeof(AT) == 4) {
        // fp32 A: 128*KDIM floats, float4 per thread-iter
#pragma unroll
        for (int i = 0; i < KDIM / 8; ++i) {    // 128*KDIM/4/256
            int c = t + i * 256;
            int row = c / (KDIM / 4);
            int kq  = (c % (KDIM / 4)) * 4;
            float4 d = make_float4(0.f, 0.f, 0.f, 0.f);
            if (row0 + row < M)
                d = *(const float4*)&A[(size_t)(row0 + row) * KDIM + kq];
            ushort4 h;
            h.x = f2bf(d.x); h.y = f2bf(d.y); h.z = f2bf(d.z); h.w = f2bf(d.w);
            *(ushort4*)&As[row * AROW + kq] = h;
        }
    } else {
        // bf16 A: 128*KDIM u16, uint4 (8 elems) per thread-iter
#pragma unroll
        for (int i = 0; i < KDIM / 16; ++i) {   // 128*KDIM/8/256
            int c = t + i * 256;
            int row = c / (KDIM / 8);
            int kq  = (c % (KDIM / 8)) * 8;
            uint4 d = make_uint4(0u, 0u, 0u, 0u);
            if (row0 + row < M)
                d = *(const uint4*)&A[(size_t)(row0 + row) * KDIM + kq];
            *(uint4*)&As[row * AROW + kq] = d;
        }
    }
    __syncthreads();

    int koff = (lane >> 4) * 8;
    int mrow = wm * 64 + (lane & 15);
    int nrow = wn * 64 + (lane & 15);

    for (int nt = 0; nt < NT; ++nt) {
        f4v acc[4][4];
#pragma unroll
        for (int i = 0; i < 4; ++i)
#pragma unroll
            for (int j = 0; j < 4; ++j)
#pragma unroll
                for (int r = 0; r < 4; ++r) acc[i][j][r] = 0.f;

        for (int k0 = 0; k0 < KDIM; k0 += 32) {
            // stage B tile 128x32 (L2-hot weights): 2 uint4 per thread
#pragma unroll
            for (int i = 0; i < 2; ++i) {
                int c = t + i * 256;
                int brow = c >> 2, kq = (c & 3) * 8;
                *(uint4*)&Bs[brow * 40 + kq] =
                    *(const uint4*)&BT[(size_t)(nt * 128 + brow) * KDIM + k0 + kq];
            }
            __syncthreads();
            s8v af[4], bf[4];
#pragma unroll
            for (int tm = 0; tm < 4; ++tm)
                af[tm] = *(const s8v*)&As[(mrow + tm * 16) * AROW + k0 + koff];
#pragma unroll
            for (int tn = 0; tn < 4; ++tn)
                bf[tn] = *(const s8v*)&Bs[(nrow + tn * 16) * 40 + koff];
#pragma unroll
            for (int tm = 0; tm < 4; ++tm)
#pragma unroll
                for (int tn = 0; tn < 4; ++tn)
                    acc[tm][tn] = __builtin_amdgcn_mfma_f32_16x16x32_bf16(
                        af[tm], bf[tn], acc[tm][tn], 0, 0, 0);
            __syncthreads();
        }

        // epilogue for this n-tile
        int buf = nt >> 1;
        u16* Cp = (buf == 0) ? C0 : (buf == 1) ? C1 : (buf == 2) ? C2 : C3;
        int stride = (buf == 0) ? s0 : (buf == 1) ? s1 : (buf == 2) ? s2 : s3;
        int colb = (nt & 1) * 128;
#pragma unroll
        for (int tm = 0; tm < 4; ++tm) {
#pragma unroll
            for (int tn = 0; tn < 4; ++tn) {
                int colg = nt * 128 + wn * 64 + tn * 16 + (lane & 15);
                int col  = colb + wn * 64 + tn * 16 + (lane & 15);
                float b = biascat[colg];
#pragma unroll
                for (int r = 0; r < 4; ++r) {
                    int row = row0 + wm * 64 + tm * 16 + (lane >> 4) * 4 + r;
                    if (row < M)
                        Cp[(size_t)row * stride + col] = f2bf(acc[tm][tn][r] + b);
                }
            }
        }
    }
}

// ---------------------------------------------------------------------------
// Attention: wave per node, 2 edges per step (lane halves), 8 cols/lane,
// kv interleaved [N][512], packed (src,ea) records, epsilon factoring.
// LAYER=1: concat + skip + relu -> bf16 [N,256]
// LAYER=2: head-mean + skip -> fp32 [N,128]
// ---------------------------------------------------------------------------
template <int LAYER>
__global__ __launch_bounds__(256) void attn_node(
    const u16* __restrict__ q, const u16* __restrict__ kv,
    const float* __restrict__ We, const u16* __restrict__ skip,
    const int* __restrict__ rowptr, const int2* __restrict__ edges,
    void* __restrict__ hout, int N)
{
    int wave = (blockIdx.x * blockDim.x + threadIdx.x) >> 6;
    int lane = threadIdx.x & 63;
    if (wave >= N) return;
    int n = wave;
    int half = lane >> 5;        // 0: edge stream A, 1: edge stream B
    int cl   = lane & 31;        // col-lane: owns cols 8*cl .. 8*cl+7
    const float scale = 0.08838834764831845f;  // 1/sqrt(128)
    const float NEG = -1e30f;

    uint4 qd = *(const uint4*)&q[(size_t)n * HC + cl * 8];
    float qf[8];
    qf[0] = bflo(qd.x); qf[1] = bfhi(qd.x);
    qf[2] = bflo(qd.y); qf[3] = bfhi(qd.y);
    qf[4] = bflo(qd.z); qf[5] = bfhi(qd.z);
    qf[6] = bflo(qd.w); qf[7] = bfhi(qd.w);
    float4 wlo = *(const float4*)&We[cl * 8];
    float4 whi = *(const float4*)&We[cl * 8 + 4];
    float wf[8] = { wlo.x, wlo.y, wlo.z, wlo.w, whi.x, whi.y, whi.z, whi.w };

    float qw = qf[0]*wf[0] + qf[1]*wf[1] + qf[2]*wf[2] + qf[3]*wf[3]
             + qf[4]*wf[4] + qf[5]*wf[5] + qf[6]*wf[6] + qf[7]*wf[7];
    qw += __shfl_xor(qw, 1);
    qw += __shfl_xor(qw, 2);
    qw += __shfl_xor(qw, 4);
    qw += __shfl_xor(qw, 8);

    int e0 = rowptr[n], e1 = rowptr[n + 1];
    float m = NEG, l = 0.f, pa = 0.f;
    float acc[8];
#pragma unroll
    for (int i = 0; i < 8; ++i) acc[i] = 0.f;

    int steps = (e1 - e0 + 1) >> 1;
    for (int st = 0; st < steps; ++st) {
        int e = e0 + 2 * st + half;
        bool act = (e < e1);
        int idx = act ? e : e0;
        int2 rec = edges[idx];
        int s = rec.x;
        float a_e = __int_as_float(rec.y);
        const u16* base = kv + (size_t)s * 512 + cl * 8;
        uint4 kd = *(const uint4*)base;          // k cols 8cl..+7
        uint4 vd = *(const uint4*)(base + 256);  // v cols 8cl..+7

        float d = qf[0] * bflo(kd.x);
        d = fmaf(qf[1], bfhi(kd.x), d);
        d = fmaf(qf[2], bflo(kd.y), d);
        d = fmaf(qf[3], bfhi(kd.y), d);
        d = fmaf(qf[4], bflo(kd.z), d);
        d = fmaf(qf[5], bfhi(kd.z), d);
        d = fmaf(qf[6], bflo(kd.w), d);
        d = fmaf(qf[7], bfhi(kd.w), d);
        d += __shfl_xor(d, 1);
        d += __shfl_xor(d, 2);
        d += __shfl_xor(d, 4);
        d += __shfl_xor(d, 8);

        float alpha = act ? fmaf(a_e, qw, d) * scale : NEG;
        float mnew = fmaxf(m, alpha);
        float corr = __expf(m - mnew);
        float p = __expf(alpha - mnew);
        p = act ? p : 0.f;
        l = fmaf(l, corr, p);
        pa = fmaf(pa, corr, p * a_e);
        acc[0] = fmaf(p, bflo(vd.x), acc[0] * corr);
        acc[1] = fmaf(p, bfhi(vd.x), acc[1] * corr);
        acc[2] = fmaf(p, bflo(vd.y), acc[2] * corr);
        acc[3] = fmaf(p, bfhi(vd.y), acc[3] * corr);
        acc[4] = fmaf(p, bflo(vd.z), acc[4] * corr);
        acc[5] = fmaf(p, bfhi(vd.z), acc[5] * corr);
        acc[6] = fmaf(p, bflo(vd.w), acc[6] * corr);
        acc[7] = fmaf(p, bfhi(vd.w), acc[7] * corr);
        m = mnew;
    }

    // merge lane-halves via xor 32
    float mo = __shfl_xor(m, 32);
    float lo = __shfl_xor(l, 32);
    float pao = __shfl_xor(pa, 32);
    float mst = fmaxf(m, mo);
    float cS = __expf(m - mst);
    float cO = __expf(mo - mst);
    l = l * cS + lo * cO;
    pa = pa * cS + pao * cO;
#pragma unroll
    for (int i = 0; i < 8; ++i) {
        float ao = __shfl_xor(acc[i], 32);
        acc[i] = acc[i] * cS + ao * cO;
    }

    float inv = (l > 0.f) ? 1.f / l : 0.f;
    float o[8];
#pragma unroll
    for (int i = 0; i < 8; ++i) o[i] = fmaf(pa, wf[i], acc[i]) * inv;

    if constexpr (LAYER == 1) {
        if (half == 0) {
            uint4 sd = *(const uint4*)&skip[(size_t)n * HC + cl * 8];
            float sf[8];
            sf[0] = bflo(sd.x); sf[1] = bfhi(sd.x);
            sf[2] = bflo(sd.y); sf[3] = bfhi(sd.y);
            sf[4] = bflo(sd.z); sf[5] = bfhi(sd.z);
            sf[6] = bflo(sd.w); sf[7] = bfhi(sd.w);
            ushort4 o4a, o4b;
            o4a.x = f2bf(fmaxf(0.f, o[0] + sf[0]));
            o4a.y = f2bf(fmaxf(0.f, o[1] + sf[1]));
            o4a.z = f2bf(fmaxf(0.f, o[2] + sf[2]));
            o4a.w = f2bf(fmaxf(0.f, o[3] + sf[3]));
            o4b.x = f2bf(fmaxf(0.f, o[4] + sf[4]));
            o4b.y = f2bf(fmaxf(0.f, o[5] + sf[5]));
            o4b.z = f2bf(fmaxf(0.f, o[6] + sf[6]));
            o4b.w = f2bf(fmaxf(0.f, o[7] + sf[7]));
            u16* hp = (u16*)hout + (size_t)n * HC + cl * 8;
            *(ushort4*)hp = o4a;
            *(ushort4*)(hp + 4) = o4b;
        }
    } else {
#pragma unroll
        for (int i = 0; i < 8; ++i) {
            float t2 = __shfl_xor(o[i], 16);
            o[i] = 0.5f * (o[i] + t2);
        }
        if (lane < 16) {
            uint4 sd = *(const uint4*)&skip[(size_t)n * HID + lane * 8];
            float sf[8];
            sf[0] = bflo(sd.x); sf[1] = bfhi(sd.x);
            sf[2] = bflo(sd.y); sf[3] = bfhi(sd.y);
            sf[4] = bflo(sd.z); sf[5] = bfhi(sd.z);
            sf[6] = bflo(sd.w); sf[7] = bfhi(sd.w);
            float* hp = (float*)hout + (size_t)n * HID + lane * 8;
            float4 oa, ob;
            oa.x = o[0] + sf[0]; oa.y = o[1] + sf[1];
            oa.z = o[2] + sf[2]; oa.w = o[3] + sf[3];
            ob.x = o[4] + sf[4]; ob.y = o[5] + sf[5];
            ob.z = o[6] + sf[6]; ob.w = o[7] + sf[7];
            *(float4*)hp = oa;
            *(float4*)(hp + 4) = ob;
        }
    }
}

// ---------------------------------------------------------------------------
// Atomic-free pooling: one wave per graph over dense h2 (batch is sorted)
// ---------------------------------------------------------------------------
__global__ __launch_bounds__(256) void pool_kernel(
    const float* __restrict__ h2, const int* __restrict__ growptr,
    float* __restrict__ out) {
    int wave = (blockIdx.x * blockDim.x + threadIdx.x) >> 6;
    int lane = threadIdx.x & 63;
    if (wave >= N_GRAPHS) return;
    int r0 = growptr[wave], r1 = growptr[wave + 1];
    float sx = 0.f, sy = 0.f;
    for (int r = r0; r < r1; ++r) {
        float2 v = *(const float2*)&h2[(size_t)r * HID + lane * 2];
        sx += v.x; sy += v.y;
    }
    float inv = 1.f / fmaxf((float)(r1 - r0), 1.f);
    float2 o; o.x = sx * inv; o.y = sy * inv;
    *(float2*)&out[(size_t)wave * HID + lane * 2] = o;
}

// ---------------------------------------------------------------------------
// Launch. ws ~123 MB (proven-safe envelope). KV = interleaved k|v [N,512].
// ---------------------------------------------------------------------------
extern "C" void kernel_launch(void* const* d_in, const int* in_sizes, int n_in,
                              void* d_out, int out_size, void* d_ws, size_t ws_size,
                              hipStream_t stream) {
    const float* x    = (const float*)d_in[0];
    const int*   ei   = (const int*)d_in[1];
    const int*   batch= (const int*)d_in[2];
    const float* ea   = (const float*)d_in[3];
    const float* Wq1  = (const float*)d_in[4];
    const float* bq1  = (const float*)d_in[5];
    const float* Wk1  = (const float*)d_in[6];
    const float* bk1  = (const float*)d_in[7];
    const float* Wv1  = (const float*)d_in[8];
    const float* bv1  = (const float*)d_in[9];
    const float* We1  = (const float*)d_in[10];
    const float* Ws1  = (const float*)d_in[11];
    const float* bs1  = (const float*)d_in[12];
    const float* Wq2  = (const float*)d_in[13];
    const float* bq2  = (const float*)d_in[14];
    const float* Wk2  = (const float*)d_in[15];
    const float* bk2  = (const float*)d_in[16];
    const float* Wv2  = (const float*)d_in[17];
    const float* bv2  = (const float*)d_in[18];
    const float* We2  = (const float*)d_in[19];
    const float* Ws2  = (const float*)d_in[20];
    const float* bs2  = (const float*)d_in[21];
    float* out = (float*)d_out;

    char* ws = (char*)d_ws;
    size_t off = 0;
    auto alloc = [&](size_t bytes) -> void* {
        void* p = ws + off;
        off += (bytes + 255) & ~(size_t)255;
        return p;
    };
    int*   flag_ei = (int*)alloc(4);
    int*   flag_b  = (int*)alloc(4);
    int*   deg     = (int*)alloc((size_t)N_NODES * 4);
    int*   rowptr  = (int*)alloc((size_t)(N_NODES + 1) * 4);
    int*   cursor  = (int*)alloc((size_t)N_NODES * 4);
    int*   bsums   = (int*)alloc(64 * 4);
    int2*  edges   = (int2*)alloc((size_t)N_EDGES * 8);
    int*   gdeg    = (int*)alloc((size_t)N_GRAPHS * 4);
    int*   growptr = (int*)alloc((size_t)(N_GRAPHS + 1) * 4);
    u16*   w1T     = (u16*)alloc((size_t)1024 * 128 * 2);
    float* b1cat   = (float*)alloc(1024 * 4);
    u16*   w2T     = (u16*)alloc((size_t)896 * 256 * 2);
    float* b2cat   = (float*)alloc(896 * 4);
    u16*   B0      = (u16*)alloc((size_t)N_NODES * HC * 2);   // q1 / h1 / h2(fp32 [N,128])
    u16*   B1      = (u16*)alloc((size_t)N_NODES * HC * 2);   // skip1 / q2
    u16*   KV      = (u16*)alloc((size_t)N_NODES * 512 * 2);  // k|v interleaved (both layers)
    u16*   B4      = (u16*)alloc((size_t)N_NODES * HID * 2);  // skip2

    hipMemsetAsync(deg, 0, (size_t)N_NODES * 4, stream);
    hipMemsetAsync(gdeg, 0, (size_t)N_GRAPHS * 4, stream);

    const int E = N_EDGES;

    detect_both_kernel<<<2, 256, 0, stream>>>(ei, batch, flag_ei, flag_b);

    hist_all_kernel<<<(E + N_NODES + 255) / 256, 256, 0, stream>>>(
        ei, batch, flag_ei, flag_b, deg, gdeg, E, N_NODES);
    int nb = (N_NODES + 1023) / 1024;  // 49
    scan_local_kernel<<<nb, 256, 0, stream>>>(deg, rowptr, bsums, N_NODES);
    scan_bsums_kernel<<<1, 64, 0, stream>>>(bsums, nb, rowptr + N_NODES);
    scan_add_kernel<<<(N_NODES + 255) / 256, 256, 0, stream>>>(rowptr, bsums, cursor, N_NODES);
    scatter_kernel<<<(E + 255) / 256, 256, 0, stream>>>(ei, ea, flag_ei, cursor, edges, E);
    scan_graph_kernel<<<1, 256, 0, stream>>>(gdeg, growptr);

    prep_w_kernel<<<(W1_ELEMS + W2_ELEMS + 255) / 256, 256, 0, stream>>>(
        Wq1, Wk1, Wv1, Ws1, bq1, bk1, bv1, bs1,
        Wq2, Wk2, Wv2, Ws2, bq2, bk2, bv2, bs2,
        w1T, b1cat, w2T, b2cat);

    int mgrid = (N_NODES + 127) / 128;  // 391

    // Layer 1: x fp32 [50000,128]; 8 n-tiles -> q(B0,256), k(KV,512), v(KV+256,512), skip(B1,256)
    gemm_slab<float, 128, 8, 8><<<mgrid, 256, 0, stream>>>(
        x, w1T, b1cat, B0, KV, KV + 256, B1, 256, 512, 512, 256, N_NODES);

    // h1 -> B0 (aliases q1; row-local, safe)
    attn_node<1><<<N_NODES / 4, 256, 0, stream>>>(B0, KV, We1, B1, rowptr, edges, B0, N_NODES);

    // Layer 2: h1 bf16 [50000,256]; 7 n-tiles -> q2(B1,256), k2(KV,512), v2(KV+256,512), skip2(B4,128)
    gemm_slab<u16, 256, 7, 8><<<mgrid, 256, 0, stream>>>(
        B0, w2T, b2cat, B1, KV, KV + 256, B4, 256, 512, 512, 128, N_NODES);

    // h2 (fp32 [N,128]) -> B0
    attn_node<2><<<N_NODES / 4, 256, 0, stream>>>(B1, KV, We2, B4, rowptr, edges, B0, N_NODES);

    pool_kernel<<<(N_GRAPHS + 3) / 4, 256, 0, stream>>>((const float*)B0, growptr, out);
}